// Round 1
// baseline (977.180 us; speedup 1.0000x reference)
//
#include <hip/hip_runtime.h>
#include <stdint.h>

#define N_NODES 50000
#define N_EDGES 300000
#define DIM_IN  1024
#define DIM_HID 512
#define DIM_OUT 30

typedef unsigned short u16;
typedef __bf16 bf16x8 __attribute__((ext_vector_type(8)));
typedef float  f32x4  __attribute__((ext_vector_type(4)));
typedef int    i32x4  __attribute__((ext_vector_type(4)));
typedef u16    u16x4  __attribute__((ext_vector_type(4)));

typedef __attribute__((address_space(3))) uint32_t lds_u32;
typedef __attribute__((address_space(1))) uint32_t gl_u32;

__device__ __forceinline__ void gllds16(const u16* g, u16* l) {
  // async global->LDS, 16B/lane; LDS dest = wave-uniform base + lane*16
  __builtin_amdgcn_global_load_lds((const gl_u32*)g, (lds_u32*)l, 16, 0, 0);
}

__device__ __forceinline__ float lrelu(float x) { return x > 0.f ? x : 0.2f * x; }
__device__ __forceinline__ float elu(float x)   { return x > 0.f ? x : __expf(x) - 1.f; }
__device__ __forceinline__ u16 f2bf(float x) {
  uint32_t u = __float_as_uint(x);
  u += 0x7fffu + ((u >> 16) & 1u);   // round-to-nearest-even
  return (u16)(u >> 16);
}

// ---------- elementwise f32 -> bf16 ----------
__global__ void k_cvt(const float* __restrict__ in, u16* __restrict__ out, int n4) {
  int i = blockIdx.x * blockDim.x + threadIdx.x;
  if (i >= n4) return;
  float4 v = ((const float4*)in)[i];
  u16x4 r = { f2bf(v.x), f2bf(v.y), f2bf(v.z), f2bf(v.w) };
  ((u16x4*)out)[i] = r;
}

// ---------- transpose + convert: in[R][C] f32 -> out[C][R] bf16 ----------
__global__ void k_transpose(const float* __restrict__ in, u16* __restrict__ out, int R, int C) {
  int r = blockIdx.x * 256 + threadIdx.x;
  int c = blockIdx.y;
  if (r < R) out[(size_t)c * R + r] = f2bf(in[(size_t)r * C + c]);
}

// ---------- bf16 MFMA GEMM: C[M][Nn] = A[M][K] * BT[Nn][K]^T ----------
// 128x128 tile, BK=32, 4 waves; global_load_lds width-16 staging.
// LDS layout: As elem offset for tid = 8*tid == (tid>>2)*32 + (tid&3)*8 (row-major 128x32).
__global__ __launch_bounds__(256) void k_gemm(const u16* __restrict__ A,
                                              const u16* __restrict__ BT,
                                              float* __restrict__ C,
                                              int M, int Nn, int K) {
  __shared__ u16 As[128 * 32];
  __shared__ u16 Bs[128 * 32];
  const int tid  = threadIdx.x;
  const int lane = tid & 63;
  const int wv   = tid >> 6;
  const int bm = blockIdx.x * 128;
  const int bn = blockIdx.y * 128;
  const int wr = (wv >> 1) * 64;
  const int wc = (wv & 1) * 64;
  const int r0 = tid >> 2;          // 0..63
  const int c0 = (tid & 3) * 8;     // 0,8,16,24 (elements)

  f32x4 acc[4][4];
#pragma unroll
  for (int i = 0; i < 4; ++i)
#pragma unroll
    for (int j = 0; j < 4; ++j) acc[i][j] = (f32x4){0.f, 0.f, 0.f, 0.f};

  int ra = bm + r0;      if (ra >= M) ra = M - 1;
  int rb = bm + r0 + 64; if (rb >= M) rb = M - 1;
  const u16* ga0 = A  + (size_t)ra * K + c0;
  const u16* ga1 = A  + (size_t)rb * K + c0;
  const u16* gb0 = BT + (size_t)(bn + r0) * K + c0;
  const u16* gb1 = BT + (size_t)(bn + r0 + 64) * K + c0;
  // wave-uniform LDS bases (elements); lane*8 elems added by HW
  u16* la0 = As + wv * 512;
  u16* la1 = As + 2048 + wv * 512;
  u16* lb0 = Bs + wv * 512;
  u16* lb1 = Bs + 2048 + wv * 512;

  const int arow = lane & 15;
  const int kcol = (lane >> 4) * 8;

  for (int k0 = 0; k0 < K; k0 += 32) {
    gllds16(ga0 + k0, la0);
    gllds16(ga1 + k0, la1);
    gllds16(gb0 + k0, lb0);
    gllds16(gb1 + k0, lb1);
    __syncthreads();
    bf16x8 af[4], bfr[4];
#pragma unroll
    for (int mi = 0; mi < 4; ++mi)
      af[mi] = *(const bf16x8*)(As + (wr + mi * 16 + arow) * 32 + kcol);
#pragma unroll
    for (int ni = 0; ni < 4; ++ni)
      bfr[ni] = *(const bf16x8*)(Bs + (wc + ni * 16 + arow) * 32 + kcol);
#pragma unroll
    for (int mi = 0; mi < 4; ++mi)
#pragma unroll
      for (int ni = 0; ni < 4; ++ni)
        acc[mi][ni] = __builtin_amdgcn_mfma_f32_16x16x32_bf16(af[mi], bfr[ni], acc[mi][ni], 0, 0, 0);
    __syncthreads();
  }

  const int crow = (lane >> 4) * 4;
  const int ccol = lane & 15;
#pragma unroll
  for (int mi = 0; mi < 4; ++mi) {
#pragma unroll
    for (int r = 0; r < 4; ++r) {
      int row = bm + wr + mi * 16 + crow + r;
      if (row < M) {
        float* cp = C + (size_t)row * Nn + bn + wc + ccol;
#pragma unroll
        for (int ni = 0; ni < 4; ++ni) cp[ni * 16] = acc[mi][ni][r];
      }
    }
  }
}

// ---------- CSR build ----------
__global__ void k_hist(const int* __restrict__ dst, int* __restrict__ counts, int E) {
  int i = blockIdx.x * blockDim.x + threadIdx.x;
  if (i < E) atomicAdd(&counts[dst[i]], 1);
}

__global__ void k_scan1(const int* __restrict__ counts, int* __restrict__ offs,
                        int* __restrict__ bsums, int n) {
  __shared__ int s[256];
  int i = blockIdx.x * 256 + threadIdx.x;
  int v = (i < n) ? counts[i] : 0;
  s[threadIdx.x] = v;
  __syncthreads();
  for (int d = 1; d < 256; d <<= 1) {
    int t = (threadIdx.x >= d) ? s[threadIdx.x - d] : 0;
    __syncthreads();
    s[threadIdx.x] += t;
    __syncthreads();
  }
  if (i < n) offs[i] = s[threadIdx.x] - v;          // block-local exclusive
  if (threadIdx.x == 255) bsums[blockIdx.x] = s[255];
}

__global__ void k_scan2(int* __restrict__ bsums, int nb) {
  __shared__ int s[256];
  int v = (threadIdx.x < nb) ? bsums[threadIdx.x] : 0;
  s[threadIdx.x] = v;
  __syncthreads();
  for (int d = 1; d < 256; d <<= 1) {
    int t = (threadIdx.x >= d) ? s[threadIdx.x - d] : 0;
    __syncthreads();
    s[threadIdx.x] += t;
    __syncthreads();
  }
  if (threadIdx.x < nb) bsums[threadIdx.x] = s[threadIdx.x] - v;  // exclusive
}

__global__ void k_scan3(int* __restrict__ offs, const int* __restrict__ bsums,
                        int* __restrict__ cursor, int n) {
  int i = blockIdx.x * 256 + threadIdx.x;
  if (i < n) {
    int o = offs[i] + bsums[blockIdx.x];
    offs[i] = o;
    cursor[i] = o;
  }
}

__global__ void k_fill(const int* __restrict__ dst, int* __restrict__ cursor,
                       int* __restrict__ eids, int E) {
  int i = blockIdx.x * blockDim.x + threadIdx.x;
  if (i < E) {
    int p = atomicAdd(&cursor[dst[i]], 1);
    eids[p] = i;
  }
}

// ---------- conv1 FUSED: single gather pass, online-softmax aggregation ----------
// Per edge: p = att.lrelu(hd+hs); rescale accumulator by exp(m-mn); acc += exp(p-mn)*hs.
// Raw score stashed in alpha[], finalized to exp(p-m)/den in a scalar pass.
__global__ __launch_bounds__(256) void k_conv1(
    const float* __restrict__ h, const int* __restrict__ src,
    const float* __restrict__ att, const int* __restrict__ offs,
    const int* __restrict__ cnts, const int* __restrict__ eids,
    float* __restrict__ alpha, float* __restrict__ h1, int nN) {
  const int lane = threadIdx.x & 63, wv = threadIdx.x >> 6;
  const int nw = gridDim.x * 4;
  for (int v = blockIdx.x * 4 + wv; v < nN; v += nw) {
    const int col = lane * 8;
    const float* hd = h + (size_t)v * DIM_HID + col;
    float4 hd0 = *(const float4*)hd, hd1 = *(const float4*)(hd + 4);
    float4 at0 = *(const float4*)(att + col), at1 = *(const float4*)(att + col + 4);
    const int o = offs[v], deg = cnts[v];
    float m = -1e30f, den = 0.f;
    float4 c0 = {0,0,0,0}, c1 = {0,0,0,0};
    // prefetch edge 0
    float4 a0 = {0,0,0,0}, a1 = {0,0,0,0};
    if (deg > 0) {
      const float* hs = h + (size_t)src[eids[o]] * DIM_HID + col;
      a0 = *(const float4*)hs; a1 = *(const float4*)(hs + 4);
    }
    for (int j = 0; j < deg; ++j) {
      float4 b0 = a0, b1 = a1;
      if (j + 1 < deg) {  // prefetch next edge while computing this one
        const float* hn = h + (size_t)src[eids[o + j + 1]] * DIM_HID + col;
        a0 = *(const float4*)hn; a1 = *(const float4*)(hn + 4);
      }
      float p;
      p  = at0.x * lrelu(hd0.x + b0.x);
      p += at0.y * lrelu(hd0.y + b0.y);
      p += at0.z * lrelu(hd0.z + b0.z);
      p += at0.w * lrelu(hd0.w + b0.w);
      p += at1.x * lrelu(hd1.x + b1.x);
      p += at1.y * lrelu(hd1.y + b1.y);
      p += at1.z * lrelu(hd1.z + b1.z);
      p += at1.w * lrelu(hd1.w + b1.w);
#pragma unroll
      for (int msk = 1; msk < 64; msk <<= 1) p += __shfl_xor(p, msk, 64);
      if (lane == 0) alpha[o + j] = p;       // raw score, finalized below
      float mn = fmaxf(m, p);
      float sc = __expf(m - mn), w = __expf(p - mn);
      den = den * sc + w;
      c0.x = c0.x * sc + w * b0.x; c0.y = c0.y * sc + w * b0.y;
      c0.z = c0.z * sc + w * b0.z; c0.w = c0.w * sc + w * b0.w;
      c1.x = c1.x * sc + w * b1.x; c1.y = c1.y * sc + w * b1.y;
      c1.z = c1.z * sc + w * b1.z; c1.w = c1.w * sc + w * b1.w;
      m = mn;
    }
    const float inv = (deg > 0) ? 1.f / den : 0.f;
    float* op = h1 + (size_t)v * DIM_HID + col;
    float4 r0 = { elu(c0.x * inv), elu(c0.y * inv), elu(c0.z * inv), elu(c0.w * inv) };
    float4 r1 = { elu(c1.x * inv), elu(c1.y * inv), elu(c1.z * inv), elu(c1.w * inv) };
    *(float4*)op = r0;
    *(float4*)(op + 4) = r1;
    // finalize alpha: scalar per edge, lane-parallel
    for (int j = lane; j < deg; j += 64)
      alpha[o + j] = __expf(alpha[o + j] - m) * inv;
  }
}

// ---------- h2 = h1 @ W2  ([N,512]x[512,30]), wave per row, W2 in LDS ----------
__global__ __launch_bounds__(256) void k_h2(const float* __restrict__ h1,
                                            const float* __restrict__ W2,
                                            float* __restrict__ out, int nN) {
  __shared__ float W2s[DIM_HID * 31];
  for (int i = threadIdx.x; i < DIM_HID * DIM_OUT; i += 256) {
    int k = i / DIM_OUT, c = i - k * DIM_OUT;
    W2s[k * 31 + c] = W2[i];
  }
  __syncthreads();
  const int lane = threadIdx.x & 63, wv = threadIdx.x >> 6;
  const int nw = gridDim.x * 4;
  for (int r = blockIdx.x * 4 + wv; r < nN; r += nw) {
    const float* hp = h1 + (size_t)r * DIM_HID;
    float acc[DIM_OUT];
#pragma unroll
    for (int c = 0; c < DIM_OUT; ++c) acc[c] = 0.f;
#pragma unroll
    for (int i = 0; i < 8; ++i) {
      float hv = hp[lane + i * 64];
      const float* w = W2s + (lane + i * 64) * 31;
#pragma unroll
      for (int c = 0; c < DIM_OUT; ++c) acc[c] += hv * w[c];
    }
#pragma unroll
    for (int c = 0; c < DIM_OUT; ++c) {
#pragma unroll
      for (int msk = 32; msk >= 1; msk >>= 1) acc[c] += __shfl_xor(acc[c], msk, 64);
    }
    if (lane == 0) {
      float* op = out + (size_t)r * DIM_OUT;
#pragma unroll
      for (int c = 0; c < DIM_OUT; ++c) op[c] = acc[c];
    }
  }
}

// ---------- conv3 aggregation in 30-dim space: agg30[v] = sum_j alpha_j * h2[src_j] ----------
// Linearity: aggregate(h2 @ W2^T) == aggregate(h2) @ W2^T. 120B/edge gather vs 2KB/edge.
// Half-wave (32 lanes) per node; lane d<30 owns one output dim.
__global__ __launch_bounds__(256) void k_agg30(
    const float* __restrict__ h2, const int* __restrict__ src,
    const int* __restrict__ offs, const int* __restrict__ cnts,
    const int* __restrict__ eids, const float* __restrict__ alpha,
    float* __restrict__ agg30, int nN) {
  int gt = blockIdx.x * 256 + threadIdx.x;
  int v = gt >> 5, d = gt & 31;
  if (v >= nN || d >= DIM_OUT) return;
  const int o = offs[v], deg = cnts[v];
  float acc = 0.f;
  for (int j = 0; j < deg; ++j) {
    const int s = src[eids[o + j]];        // broadcast within half-wave
    acc += alpha[o + j] * h2[(size_t)s * DIM_OUT + d];
  }
  agg30[(size_t)v * DIM_OUT + d] = acc;
}

// ---------- h3 = elu(agg30 @ W2^T) -> bf16  ([N,30]x[30,512]) ----------
__global__ __launch_bounds__(256) void k_g3(const float* __restrict__ agg30,
                                            const float* __restrict__ W2,
                                            u16* __restrict__ h3b, int nN) {
  __shared__ float W2s[DIM_HID * 31];
  for (int i = threadIdx.x; i < DIM_HID * DIM_OUT; i += 256) {
    int k = i / DIM_OUT, c = i - k * DIM_OUT;
    W2s[k * 31 + c] = W2[i];
  }
  __syncthreads();
  const int lane = threadIdx.x & 63, wv = threadIdx.x >> 6;
  const int nw = gridDim.x * 4;
  for (int r = blockIdx.x * 4 + wv; r < nN; r += nw) {
    float hv[DIM_OUT];
    const float* hp = agg30 + (size_t)r * DIM_OUT;
#pragma unroll
    for (int c = 0; c < DIM_OUT; ++c) hv[c] = hp[c];
#pragma unroll
    for (int t = 0; t < 8; ++t) {
      int n = lane + t * 64;
      const float* w = W2s + n * 31;
      float a = 0.f;
#pragma unroll
      for (int c = 0; c < DIM_OUT; ++c) a += hv[c] * w[c];
      h3b[(size_t)r * DIM_HID + n] = f2bf(elu(a));
    }
  }
}

extern "C" void kernel_launch(void* const* d_in, const int* in_sizes, int n_in,
                              void* d_out, int out_size, void* d_ws, size_t ws_size,
                              hipStream_t stream) {
  const float* features = (const float*)d_in[0];
  const int*   eidx     = (const int*)d_in[1];
  const float* W1       = (const float*)d_in[2];
  const float* att1     = (const float*)d_in[3];
  const float* W2       = (const float*)d_in[4];
  const float* W4       = (const float*)d_in[5];
  const int* srcI = eidx;
  const int* dstI = eidx + N_EDGES;
  float* out = (float*)d_out;

  char* ws = (char*)d_ws;
  size_t off = 0;
  auto alloc = [&](size_t b) -> void* {
    void* p = ws + off;
    off += (b + 255) & ~(size_t)255;
    return p;
  };
  u16*   Xb     = (u16*)  alloc((size_t)N_NODES * DIM_IN * 2);   // later reused as h3 bf16
  u16*   W1T    = (u16*)  alloc((size_t)DIM_HID * DIM_IN * 2);
  u16*   W4T    = (u16*)  alloc((size_t)DIM_IN * DIM_HID * 2);
  float* h      = (float*)alloc((size_t)N_NODES * DIM_HID * 4);
  float* h1     = (float*)alloc((size_t)N_NODES * DIM_HID * 4);
  int*   counts = (int*)  alloc((size_t)N_NODES * 4);
  int*   offs   = (int*)  alloc((size_t)N_NODES * 4);
  int*   cursor = (int*)  alloc((size_t)N_NODES * 4);
  int*   bsums  = (int*)  alloc(1024);
  int*   eids   = (int*)  alloc((size_t)N_EDGES * 4);
  float* alpha  = (float*)alloc((size_t)N_EDGES * 4);
  float* agg30  = (float*)alloc((size_t)N_NODES * DIM_OUT * 4);
  u16*   h3b    = Xb;

  // 1. convert inputs to bf16 (+ transposed weights for MFMA B-operand)
  k_cvt<<<(N_NODES * DIM_IN / 4 + 255) / 256, 256, 0, stream>>>(features, Xb, N_NODES * DIM_IN / 4);
  k_transpose<<<dim3(DIM_IN / 256, DIM_HID), 256, 0, stream>>>(W1, W1T, DIM_IN, DIM_HID);
  k_transpose<<<dim3(DIM_HID / 256, DIM_IN), 256, 0, stream>>>(W4, W4T, DIM_HID, DIM_IN);

  // 2. h = X @ W1  (f32 out)
  k_gemm<<<dim3((N_NODES + 127) / 128, DIM_HID / 128), 256, 0, stream>>>(
      Xb, W1T, h, N_NODES, DIM_HID, DIM_IN);

  // 3. CSR by dst
  hipMemsetAsync(counts, 0, (size_t)N_NODES * 4, stream);
  k_hist<<<(N_EDGES + 255) / 256, 256, 0, stream>>>(dstI, counts, N_EDGES);
  const int nScanBlocks = (N_NODES + 255) / 256;  // 196
  k_scan1<<<nScanBlocks, 256, 0, stream>>>(counts, offs, bsums, N_NODES);
  k_scan2<<<1, 256, 0, stream>>>(bsums, nScanBlocks);
  k_scan3<<<nScanBlocks, 256, 0, stream>>>(offs, bsums, cursor, N_NODES);
  k_fill<<<(N_EDGES + 255) / 256, 256, 0, stream>>>(dstI, cursor, eids, N_EDGES);

  // 4. conv1 fused: scores + online softmax + aggregate + ELU (one gather pass)
  k_conv1<<<N_NODES / 4, 256, 0, stream>>>(h, srcI, att1, offs, counts, eids, alpha, h1, N_NODES);

  // 5. h2 = h1 @ W2 -> out[0 : N*30)
  k_h2<<<1024, 256, 0, stream>>>(h1, W2, out, N_NODES);

  // 6. conv3 aggregation in 30-dim space (linearity of aggregate over W2^T)
  k_agg30<<<(N_NODES * 32 + 255) / 256, 256, 0, stream>>>(
      out, srcI, offs, counts, eids, alpha, agg30, N_NODES);

  // 7. h3 = elu(agg30 @ W2^T) -> bf16 (aliases Xb)
  k_g3<<<1024, 256, 0, stream>>>(agg30, W2, h3b, N_NODES);

  // 8. h4 = h3 @ W4 -> out[N*30 : )
  k_gemm<<<dim3((N_NODES + 127) / 128, DIM_IN / 128), 256, 0, stream>>>(
      h3b, W4T, out + (size_t)N_NODES * DIM_OUT, N_NODES, DIM_IN, DIM_HID);
}

// Round 2
// 833.771 us; speedup vs baseline: 1.1720x; 1.1720x over previous
//
#include <hip/hip_runtime.h>
#include <stdint.h>

#define N_NODES 50000
#define N_EDGES 300000
#define DIM_IN  1024
#define DIM_HID 512
#define DIM_OUT 30

typedef unsigned short u16;
typedef __bf16 bf16x8 __attribute__((ext_vector_type(8)));
typedef float  f32x4  __attribute__((ext_vector_type(4)));
typedef int    i32x4  __attribute__((ext_vector_type(4)));
typedef u16    u16x4  __attribute__((ext_vector_type(4)));
typedef u16    u16x8  __attribute__((ext_vector_type(8)));

typedef __attribute__((address_space(3))) uint32_t lds_u32;
typedef __attribute__((address_space(1))) uint32_t gl_u32;

__device__ __forceinline__ void gllds16(const u16* g, u16* l) {
  // async global->LDS, 16B/lane; LDS dest = wave-uniform base + lane*16
  __builtin_amdgcn_global_load_lds((const gl_u32*)g, (lds_u32*)l, 16, 0, 0);
}

__device__ __forceinline__ float lrelu(float x) { return x > 0.f ? x : 0.2f * x; }
__device__ __forceinline__ float elu(float x)   { return x > 0.f ? x : __expf(x) - 1.f; }
__device__ __forceinline__ u16 f2bf(float x) {
  uint32_t u = __float_as_uint(x);
  u += 0x7fffu + ((u >> 16) & 1u);   // round-to-nearest-even
  return (u16)(u >> 16);
}
__device__ __forceinline__ float bf2f(u16 b) {
  return __uint_as_float((uint32_t)b << 16);
}

// ---------- elementwise f32 -> bf16 ----------
__global__ void k_cvt(const float* __restrict__ in, u16* __restrict__ out, int n4) {
  int i = blockIdx.x * blockDim.x + threadIdx.x;
  if (i >= n4) return;
  float4 v = ((const float4*)in)[i];
  u16x4 r = { f2bf(v.x), f2bf(v.y), f2bf(v.z), f2bf(v.w) };
  ((u16x4*)out)[i] = r;
}

// ---------- transpose + convert: in[R][C] f32 -> out[C][R] bf16 ----------
__global__ void k_transpose(const float* __restrict__ in, u16* __restrict__ out, int R, int C) {
  int r = blockIdx.x * 256 + threadIdx.x;
  int c = blockIdx.y;
  if (r < R) out[(size_t)c * R + r] = f2bf(in[(size_t)r * C + c]);
}

// ---------- W2 [512][30] f32 -> W2T hi/lo bf16 [32][512] (rows 30,31 zero) ----------
__global__ void k_w2t(const float* __restrict__ W2, u16* __restrict__ hiT, u16* __restrict__ loT) {
  int i = blockIdx.x * 256 + threadIdx.x;
  if (i >= 32 * 512) return;
  int c = i >> 9, k = i & 511;                  // c = out row (col of W2), k
  float v = (c < DIM_OUT) ? W2[(size_t)k * DIM_OUT + c] : 0.f;
  u16 hb = f2bf(v);
  hiT[i] = hb;
  loT[i] = f2bf(v - bf2f(hb));
}

// ---------- bf16 MFMA GEMM: C[M][Nn] = A[M][K] * BT[Nn][K]^T ----------
// 128x128 tile, BK=32, 4 waves; global_load_lds width-16 staging.
__global__ __launch_bounds__(256) void k_gemm(const u16* __restrict__ A,
                                              const u16* __restrict__ BT,
                                              float* __restrict__ C,
                                              int M, int Nn, int K) {
  __shared__ u16 As[128 * 32];
  __shared__ u16 Bs[128 * 32];
  const int tid  = threadIdx.x;
  const int lane = tid & 63;
  const int wv   = tid >> 6;
  const int bm = blockIdx.x * 128;
  const int bn = blockIdx.y * 128;
  const int wr = (wv >> 1) * 64;
  const int wc = (wv & 1) * 64;
  const int r0 = tid >> 2;          // 0..63
  const int c0 = (tid & 3) * 8;     // 0,8,16,24 (elements)

  f32x4 acc[4][4];
#pragma unroll
  for (int i = 0; i < 4; ++i)
#pragma unroll
    for (int j = 0; j < 4; ++j) acc[i][j] = (f32x4){0.f, 0.f, 0.f, 0.f};

  int ra = bm + r0;      if (ra >= M) ra = M - 1;
  int rb = bm + r0 + 64; if (rb >= M) rb = M - 1;
  const u16* ga0 = A  + (size_t)ra * K + c0;
  const u16* ga1 = A  + (size_t)rb * K + c0;
  const u16* gb0 = BT + (size_t)(bn + r0) * K + c0;
  const u16* gb1 = BT + (size_t)(bn + r0 + 64) * K + c0;
  u16* la0 = As + wv * 512;
  u16* la1 = As + 2048 + wv * 512;
  u16* lb0 = Bs + wv * 512;
  u16* lb1 = Bs + 2048 + wv * 512;

  const int arow = lane & 15;
  const int kcol = (lane >> 4) * 8;

  for (int k0 = 0; k0 < K; k0 += 32) {
    gllds16(ga0 + k0, la0);
    gllds16(ga1 + k0, la1);
    gllds16(gb0 + k0, lb0);
    gllds16(gb1 + k0, lb1);
    __syncthreads();
    bf16x8 af[4], bfr[4];
#pragma unroll
    for (int mi = 0; mi < 4; ++mi)
      af[mi] = *(const bf16x8*)(As + (wr + mi * 16 + arow) * 32 + kcol);
#pragma unroll
    for (int ni = 0; ni < 4; ++ni)
      bfr[ni] = *(const bf16x8*)(Bs + (wc + ni * 16 + arow) * 32 + kcol);
#pragma unroll
    for (int mi = 0; mi < 4; ++mi)
#pragma unroll
      for (int ni = 0; ni < 4; ++ni)
        acc[mi][ni] = __builtin_amdgcn_mfma_f32_16x16x32_bf16(af[mi], bfr[ni], acc[mi][ni], 0, 0, 0);
    __syncthreads();
  }

  const int crow = (lane >> 4) * 4;
  const int ccol = lane & 15;
#pragma unroll
  for (int mi = 0; mi < 4; ++mi) {
#pragma unroll
    for (int r = 0; r < 4; ++r) {
      int row = bm + wr + mi * 16 + crow + r;
      if (row < M) {
        float* cp = C + (size_t)row * Nn + bn + wc + ccol;
#pragma unroll
        for (int ni = 0; ni < 4; ++ni) cp[ni * 16] = acc[mi][ni][r];
      }
    }
  }
}

// ---------- h2 = h1 @ W2 via split-bf16 MFMA (hi/lo 3-product, ~f32 accuracy) ----------
// A: h1 hi/lo bf16 [M][512] (from k_conv1). B: W2T hi/lo bf16 [32][512] (padded).
// Block = 256 thr / 4 waves, 256 rows per block (64/wave), N = 32 (30 used).
__global__ __launch_bounds__(256) void k_h2m(const u16* __restrict__ Ahi,
                                             const u16* __restrict__ Alo,
                                             const u16* __restrict__ Bhig,
                                             const u16* __restrict__ Blog,
                                             float* __restrict__ C, int M) {
  __shared__ u16 Bh[32 * 520];   // padded row stride 520: 2-way bank aliasing only
  __shared__ u16 Bl[32 * 520];
  const int tid = threadIdx.x, lane = tid & 63, wv = tid >> 6;
  // stage W2T into padded LDS (coalesced 16B chunks)
  for (int idx = tid; idx < 2048; idx += 256) {
    int e = idx * 8;
    int row = e >> 9, k = e & 511;
    *(u16x8*)(Bh + row * 520 + k) = *(const u16x8*)(Bhig + e);
    *(u16x8*)(Bl + row * 520 + k) = *(const u16x8*)(Blog + e);
  }
  __syncthreads();

  const int bm = blockIdx.x * 256 + wv * 64;
  const int arow = lane & 15, koff = (lane >> 4) * 8;

  f32x4 acc[4][2];
#pragma unroll
  for (int mi = 0; mi < 4; ++mi)
#pragma unroll
    for (int ni = 0; ni < 2; ++ni) acc[mi][ni] = (f32x4){0.f, 0.f, 0.f, 0.f};

  const u16* pah[4]; const u16* pal[4];
#pragma unroll
  for (int mi = 0; mi < 4; ++mi) {
    int r = bm + mi * 16 + arow; if (r >= M) r = M - 1;
    pah[mi] = Ahi + (size_t)r * DIM_HID + koff;
    pal[mi] = Alo + (size_t)r * DIM_HID + koff;
  }
  const u16* pbh[2]; const u16* pbl[2];
#pragma unroll
  for (int ni = 0; ni < 2; ++ni) {
    pbh[ni] = Bh + (ni * 16 + arow) * 520 + koff;
    pbl[ni] = Bl + (ni * 16 + arow) * 520 + koff;
  }

#pragma unroll
  for (int kk = 0; kk < 16; ++kk) {
    const int k0 = kk * 32;
    bf16x8 ah[4], al[4], bh[2], bl[2];
#pragma unroll
    for (int mi = 0; mi < 4; ++mi) {
      ah[mi] = *(const bf16x8*)(pah[mi] + k0);
      al[mi] = *(const bf16x8*)(pal[mi] + k0);
    }
#pragma unroll
    for (int ni = 0; ni < 2; ++ni) {
      bh[ni] = *(const bf16x8*)(pbh[ni] + k0);
      bl[ni] = *(const bf16x8*)(pbl[ni] + k0);
    }
#pragma unroll
    for (int mi = 0; mi < 4; ++mi)
#pragma unroll
      for (int ni = 0; ni < 2; ++ni) {
        acc[mi][ni] = __builtin_amdgcn_mfma_f32_16x16x32_bf16(ah[mi], bh[ni], acc[mi][ni], 0, 0, 0);
        acc[mi][ni] = __builtin_amdgcn_mfma_f32_16x16x32_bf16(al[mi], bh[ni], acc[mi][ni], 0, 0, 0);
        acc[mi][ni] = __builtin_amdgcn_mfma_f32_16x16x32_bf16(ah[mi], bl[ni], acc[mi][ni], 0, 0, 0);
      }
  }

  const int crow = (lane >> 4) * 4, ccol = lane & 15;
#pragma unroll
  for (int mi = 0; mi < 4; ++mi) {
#pragma unroll
    for (int r = 0; r < 4; ++r) {
      int row = bm + mi * 16 + crow + r;
      if (row < M) {
#pragma unroll
        for (int ni = 0; ni < 2; ++ni) {
          int col = ni * 16 + ccol;
          if (col < DIM_OUT) C[(size_t)row * DIM_OUT + col] = acc[mi][ni][r];
        }
      }
    }
  }
}

// ---------- CSR build ----------
__global__ void k_hist(const int* __restrict__ dst, int* __restrict__ counts, int E) {
  int i = blockIdx.x * blockDim.x + threadIdx.x;
  if (i < E) atomicAdd(&counts[dst[i]], 1);
}

__global__ void k_scan1(const int* __restrict__ counts, int* __restrict__ offs,
                        int* __restrict__ bsums, int n) {
  __shared__ int s[256];
  int i = blockIdx.x * 256 + threadIdx.x;
  int v = (i < n) ? counts[i] : 0;
  s[threadIdx.x] = v;
  __syncthreads();
  for (int d = 1; d < 256; d <<= 1) {
    int t = (threadIdx.x >= d) ? s[threadIdx.x - d] : 0;
    __syncthreads();
    s[threadIdx.x] += t;
    __syncthreads();
  }
  if (i < n) offs[i] = s[threadIdx.x] - v;          // block-local exclusive
  if (threadIdx.x == 255) bsums[blockIdx.x] = s[255];
}

__global__ void k_scan2(int* __restrict__ bsums, int nb) {
  __shared__ int s[256];
  int v = (threadIdx.x < nb) ? bsums[threadIdx.x] : 0;
  s[threadIdx.x] = v;
  __syncthreads();
  for (int d = 1; d < 256; d <<= 1) {
    int t = (threadIdx.x >= d) ? s[threadIdx.x - d] : 0;
    __syncthreads();
    s[threadIdx.x] += t;
    __syncthreads();
  }
  if (threadIdx.x < nb) bsums[threadIdx.x] = s[threadIdx.x] - v;  // exclusive
}

__global__ void k_scan3(int* __restrict__ offs, const int* __restrict__ bsums,
                        int* __restrict__ cursor, int n) {
  int i = blockIdx.x * 256 + threadIdx.x;
  if (i < n) {
    int o = offs[i] + bsums[blockIdx.x];
    offs[i] = o;
    cursor[i] = o;
  }
}

__global__ void k_fill(const int* __restrict__ dst, int* __restrict__ cursor,
                       int* __restrict__ eids, int E) {
  int i = blockIdx.x * blockDim.x + threadIdx.x;
  if (i < E) {
    int p = atomicAdd(&cursor[dst[i]], 1);
    eids[p] = i;
  }
}

// ---------- conv1 FUSED: single gather pass, online-softmax aggregation ----------
// Emits h1 as split bf16 (hi + lo) for the MFMA h2 GEMM.
__global__ __launch_bounds__(256) void k_conv1(
    const float* __restrict__ h, const int* __restrict__ src,
    const float* __restrict__ att, const int* __restrict__ offs,
    const int* __restrict__ cnts, const int* __restrict__ eids,
    float* __restrict__ alpha, u16* __restrict__ h1hi, u16* __restrict__ h1lo, int nN) {
  const int lane = threadIdx.x & 63, wv = threadIdx.x >> 6;
  const int nw = gridDim.x * 4;
  for (int v = blockIdx.x * 4 + wv; v < nN; v += nw) {
    const int col = lane * 8;
    const float* hd = h + (size_t)v * DIM_HID + col;
    float4 hd0 = *(const float4*)hd, hd1 = *(const float4*)(hd + 4);
    float4 at0 = *(const float4*)(att + col), at1 = *(const float4*)(att + col + 4);
    const int o = offs[v], deg = cnts[v];
    float m = -1e30f, den = 0.f;
    float4 c0 = {0,0,0,0}, c1 = {0,0,0,0};
    float4 a0 = {0,0,0,0}, a1 = {0,0,0,0};
    if (deg > 0) {
      const float* hs = h + (size_t)src[eids[o]] * DIM_HID + col;
      a0 = *(const float4*)hs; a1 = *(const float4*)(hs + 4);
    }
    for (int j = 0; j < deg; ++j) {
      float4 b0 = a0, b1 = a1;
      if (j + 1 < deg) {  // prefetch next edge while computing this one
        const float* hn = h + (size_t)src[eids[o + j + 1]] * DIM_HID + col;
        a0 = *(const float4*)hn; a1 = *(const float4*)(hn + 4);
      }
      float p;
      p  = at0.x * lrelu(hd0.x + b0.x);
      p += at0.y * lrelu(hd0.y + b0.y);
      p += at0.z * lrelu(hd0.z + b0.z);
      p += at0.w * lrelu(hd0.w + b0.w);
      p += at1.x * lrelu(hd1.x + b1.x);
      p += at1.y * lrelu(hd1.y + b1.y);
      p += at1.z * lrelu(hd1.z + b1.z);
      p += at1.w * lrelu(hd1.w + b1.w);
#pragma unroll
      for (int msk = 1; msk < 64; msk <<= 1) p += __shfl_xor(p, msk, 64);
      if (lane == 0) alpha[o + j] = p;       // raw score, finalized below
      float mn = fmaxf(m, p);
      float sc = __expf(m - mn), w = __expf(p - mn);
      den = den * sc + w;
      c0.x = c0.x * sc + w * b0.x; c0.y = c0.y * sc + w * b0.y;
      c0.z = c0.z * sc + w * b0.z; c0.w = c0.w * sc + w * b0.w;
      c1.x = c1.x * sc + w * b1.x; c1.y = c1.y * sc + w * b1.y;
      c1.z = c1.z * sc + w * b1.z; c1.w = c1.w * sc + w * b1.w;
      m = mn;
    }
    const float inv = (deg > 0) ? 1.f / den : 0.f;
    float rv[8] = { elu(c0.x * inv), elu(c0.y * inv), elu(c0.z * inv), elu(c0.w * inv),
                    elu(c1.x * inv), elu(c1.y * inv), elu(c1.z * inv), elu(c1.w * inv) };
    u16x8 hi8, lo8;
#pragma unroll
    for (int i = 0; i < 8; ++i) {
      u16 hb = f2bf(rv[i]);
      hi8[i] = hb;
      lo8[i] = f2bf(rv[i] - bf2f(hb));
    }
    *(u16x8*)(h1hi + (size_t)v * DIM_HID + col) = hi8;
    *(u16x8*)(h1lo + (size_t)v * DIM_HID + col) = lo8;
    // finalize alpha: scalar per edge, lane-parallel
    for (int j = lane; j < deg; j += 64)
      alpha[o + j] = __expf(alpha[o + j] - m) * inv;
  }
}

// ---------- conv3 aggregation in 30-dim space ----------
__global__ __launch_bounds__(256) void k_agg30(
    const float* __restrict__ h2, const int* __restrict__ src,
    const int* __restrict__ offs, const int* __restrict__ cnts,
    const int* __restrict__ eids, const float* __restrict__ alpha,
    float* __restrict__ agg30, int nN) {
  int gt = blockIdx.x * 256 + threadIdx.x;
  int v = gt >> 5, d = gt & 31;
  if (v >= nN || d >= DIM_OUT) return;
  const int o = offs[v], deg = cnts[v];
  float acc = 0.f;
  for (int j = 0; j < deg; ++j) {
    const int s = src[eids[o + j]];        // broadcast within half-wave
    acc += alpha[o + j] * h2[(size_t)s * DIM_OUT + d];
  }
  agg30[(size_t)v * DIM_OUT + d] = acc;
}

// ---------- h3 = elu(agg30 @ W2^T) -> bf16  ([N,30]x[30,512]) ----------
__global__ __launch_bounds__(256) void k_g3(const float* __restrict__ agg30,
                                            const float* __restrict__ W2,
                                            u16* __restrict__ h3b, int nN) {
  __shared__ float W2s[DIM_HID * 31];
  for (int i = threadIdx.x; i < DIM_HID * DIM_OUT; i += 256) {
    int k = i / DIM_OUT, c = i - k * DIM_OUT;
    W2s[k * 31 + c] = W2[i];
  }
  __syncthreads();
  const int lane = threadIdx.x & 63, wv = threadIdx.x >> 6;
  const int nw = gridDim.x * 4;
  for (int r = blockIdx.x * 4 + wv; r < nN; r += nw) {
    float hv[DIM_OUT];
    const float* hp = agg30 + (size_t)r * DIM_OUT;
#pragma unroll
    for (int c = 0; c < DIM_OUT; ++c) hv[c] = hp[c];
#pragma unroll
    for (int t = 0; t < 8; ++t) {
      int n = lane + t * 64;
      const float* w = W2s + n * 31;
      float a = 0.f;
#pragma unroll
      for (int c = 0; c < DIM_OUT; ++c) a += hv[c] * w[c];
      h3b[(size_t)r * DIM_HID + n] = f2bf(elu(a));
    }
  }
}

extern "C" void kernel_launch(void* const* d_in, const int* in_sizes, int n_in,
                              void* d_out, int out_size, void* d_ws, size_t ws_size,
                              hipStream_t stream) {
  const float* features = (const float*)d_in[0];
  const int*   eidx     = (const int*)d_in[1];
  const float* W1       = (const float*)d_in[2];
  const float* att1     = (const float*)d_in[3];
  const float* W2       = (const float*)d_in[4];
  const float* W4       = (const float*)d_in[5];
  const int* srcI = eidx;
  const int* dstI = eidx + N_EDGES;
  float* out = (float*)d_out;

  char* ws = (char*)d_ws;
  size_t off = 0;
  auto alloc = [&](size_t b) -> void* {
    void* p = ws + off;
    off += (b + 255) & ~(size_t)255;
    return p;
  };
  u16*   Xb     = (u16*)  alloc((size_t)N_NODES * DIM_IN * 2);   // later reused as h3 bf16
  u16*   W1T    = (u16*)  alloc((size_t)DIM_HID * DIM_IN * 2);
  u16*   W4T    = (u16*)  alloc((size_t)DIM_IN * DIM_HID * 2);
  float* h      = (float*)alloc((size_t)N_NODES * DIM_HID * 4);
  u16*   h1hi   = (u16*)  alloc((size_t)N_NODES * DIM_HID * 2);
  u16*   h1lo   = (u16*)  alloc((size_t)N_NODES * DIM_HID * 2);
  u16*   W2Thi  = (u16*)  alloc((size_t)32 * DIM_HID * 2);
  u16*   W2Tlo  = (u16*)  alloc((size_t)32 * DIM_HID * 2);
  int*   counts = (int*)  alloc((size_t)N_NODES * 4);
  int*   offs   = (int*)  alloc((size_t)N_NODES * 4);
  int*   cursor = (int*)  alloc((size_t)N_NODES * 4);
  int*   bsums  = (int*)  alloc(1024);
  int*   eids   = (int*)  alloc((size_t)N_EDGES * 4);
  float* alpha  = (float*)alloc((size_t)N_EDGES * 4);
  float* agg30  = (float*)alloc((size_t)N_NODES * DIM_OUT * 4);
  u16*   h3b    = Xb;

  // 1. convert inputs to bf16 (+ transposed weights for MFMA B-operand)
  k_cvt<<<(N_NODES * DIM_IN / 4 + 255) / 256, 256, 0, stream>>>(features, Xb, N_NODES * DIM_IN / 4);
  k_transpose<<<dim3(DIM_IN / 256, DIM_HID), 256, 0, stream>>>(W1, W1T, DIM_IN, DIM_HID);
  k_transpose<<<dim3(DIM_HID / 256, DIM_IN), 256, 0, stream>>>(W4, W4T, DIM_HID, DIM_IN);
  k_w2t<<<(32 * DIM_HID + 255) / 256, 256, 0, stream>>>(W2, W2Thi, W2Tlo);

  // 2. h = X @ W1  (f32 out)
  k_gemm<<<dim3((N_NODES + 127) / 128, DIM_HID / 128), 256, 0, stream>>>(
      Xb, W1T, h, N_NODES, DIM_HID, DIM_IN);

  // 3. CSR by dst
  hipMemsetAsync(counts, 0, (size_t)N_NODES * 4, stream);
  k_hist<<<(N_EDGES + 255) / 256, 256, 0, stream>>>(dstI, counts, N_EDGES);
  const int nScanBlocks = (N_NODES + 255) / 256;  // 196
  k_scan1<<<nScanBlocks, 256, 0, stream>>>(counts, offs, bsums, N_NODES);
  k_scan2<<<1, 256, 0, stream>>>(bsums, nScanBlocks);
  k_scan3<<<nScanBlocks, 256, 0, stream>>>(offs, bsums, cursor, N_NODES);
  k_fill<<<(N_EDGES + 255) / 256, 256, 0, stream>>>(dstI, cursor, eids, N_EDGES);

  // 4. conv1 fused: scores + online softmax + aggregate + ELU (one gather pass)
  k_conv1<<<N_NODES / 4, 256, 0, stream>>>(h, srcI, att1, offs, counts, eids, alpha,
                                           h1hi, h1lo, N_NODES);

  // 5. h2 = h1 @ W2 -> out[0 : N*30) via split-bf16 MFMA
  k_h2m<<<(N_NODES + 255) / 256, 256, 0, stream>>>(h1hi, h1lo, W2Thi, W2Tlo, out, N_NODES);

  // 6. conv3 aggregation in 30-dim space (linearity of aggregate over W2^T)
  k_agg30<<<(N_NODES * 32 + 255) / 256, 256, 0, stream>>>(
      out, srcI, offs, counts, eids, alpha, agg30, N_NODES);

  // 7. h3 = elu(agg30 @ W2^T) -> bf16 (aliases Xb)
  k_g3<<<1024, 256, 0, stream>>>(agg30, W2, h3b, N_NODES);

  // 8. h4 = h3 @ W4 -> out[N*30 : )
  k_gemm<<<dim3((N_NODES + 127) / 128, DIM_IN / 128), 256, 0, stream>>>(
      h3b, W4T, out + (size_t)N_NODES * DIM_OUT, N_NODES, DIM_IN, DIM_HID);
}

// Round 3
// 808.221 us; speedup vs baseline: 1.2091x; 1.0316x over previous
//
#include <hip/hip_runtime.h>
#include <stdint.h>

#define N_NODES 50000
#define N_EDGES 300000
#define DIM_IN  1024
#define DIM_HID 512
#define DIM_OUT 30

typedef unsigned short u16;
typedef __bf16 bf16x8 __attribute__((ext_vector_type(8)));
typedef float  f32x4  __attribute__((ext_vector_type(4)));
typedef int    i32x4  __attribute__((ext_vector_type(4)));
typedef u16    u16x4  __attribute__((ext_vector_type(4)));
typedef u16    u16x8  __attribute__((ext_vector_type(8)));

typedef __attribute__((address_space(3))) uint32_t lds_u32;
typedef __attribute__((address_space(1))) uint32_t gl_u32;

__device__ __forceinline__ void gllds16(const u16* g, u16* l) {
  // async global->LDS, 16B/lane; LDS dest = wave-uniform base + lane*16
  __builtin_amdgcn_global_load_lds((const gl_u32*)g, (lds_u32*)l, 16, 0, 0);
}

__device__ __forceinline__ float lrelu(float x) { return x > 0.f ? x : 0.2f * x; }
__device__ __forceinline__ float elu(float x)   { return x > 0.f ? x : __expf(x) - 1.f; }
__device__ __forceinline__ u16 f2bf(float x) {
  uint32_t u = __float_as_uint(x);
  u += 0x7fffu + ((u >> 16) & 1u);   // round-to-nearest-even
  return (u16)(u >> 16);
}
__device__ __forceinline__ float bf2f(u16 b) {
  return __uint_as_float((uint32_t)b << 16);
}

// ---------- elementwise f32 -> bf16 ----------
__global__ void k_cvt(const float* __restrict__ in, u16* __restrict__ out, int n4) {
  int i = blockIdx.x * blockDim.x + threadIdx.x;
  if (i >= n4) return;
  float4 v = ((const float4*)in)[i];
  u16x4 r = { f2bf(v.x), f2bf(v.y), f2bf(v.z), f2bf(v.w) };
  ((u16x4*)out)[i] = r;
}

// ---------- transpose + convert: in[R][C] f32 -> out[C][R] bf16 ----------
__global__ void k_transpose(const float* __restrict__ in, u16* __restrict__ out, int R, int C) {
  int r = blockIdx.x * 256 + threadIdx.x;
  int c = blockIdx.y;
  if (r < R) out[(size_t)c * R + r] = f2bf(in[(size_t)r * C + c]);
}

// ---------- W2 [512][30] f32 -> W2T hi/lo bf16 [32][512] (rows 30,31 zero) ----------
__global__ void k_w2t(const float* __restrict__ W2, u16* __restrict__ hiT, u16* __restrict__ loT) {
  int i = blockIdx.x * 256 + threadIdx.x;
  if (i >= 32 * 512) return;
  int c = i >> 9, k = i & 511;                  // c = out row (col of W2), k
  float v = (c < DIM_OUT) ? W2[(size_t)k * DIM_OUT + c] : 0.f;
  u16 hb = f2bf(v);
  hiT[i] = hb;
  loT[i] = f2bf(v - bf2f(hb));
}

// ---------- bf16 MFMA GEMM: C[M][Nn] = A[M][K] * BT[Nn][K]^T ----------
// 128x128 tile, BK=32, 4 waves; global_load_lds width-16 staging.
// BF16OUT: store C as bf16 (halves write traffic when consumer tolerates bf16).
template<bool BF16OUT>
__global__ __launch_bounds__(256) void k_gemm(const u16* __restrict__ A,
                                              const u16* __restrict__ BT,
                                              void* __restrict__ Cv,
                                              int M, int Nn, int K) {
  __shared__ u16 As[128 * 32];
  __shared__ u16 Bs[128 * 32];
  const int tid  = threadIdx.x;
  const int lane = tid & 63;
  const int wv   = tid >> 6;
  const int bm = blockIdx.x * 128;
  const int bn = blockIdx.y * 128;
  const int wr = (wv >> 1) * 64;
  const int wc = (wv & 1) * 64;
  const int r0 = tid >> 2;          // 0..63
  const int c0 = (tid & 3) * 8;     // 0,8,16,24 (elements)

  f32x4 acc[4][4];
#pragma unroll
  for (int i = 0; i < 4; ++i)
#pragma unroll
    for (int j = 0; j < 4; ++j) acc[i][j] = (f32x4){0.f, 0.f, 0.f, 0.f};

  int ra = bm + r0;      if (ra >= M) ra = M - 1;
  int rb = bm + r0 + 64; if (rb >= M) rb = M - 1;
  const u16* ga0 = A  + (size_t)ra * K + c0;
  const u16* ga1 = A  + (size_t)rb * K + c0;
  const u16* gb0 = BT + (size_t)(bn + r0) * K + c0;
  const u16* gb1 = BT + (size_t)(bn + r0 + 64) * K + c0;
  u16* la0 = As + wv * 512;
  u16* la1 = As + 2048 + wv * 512;
  u16* lb0 = Bs + wv * 512;
  u16* lb1 = Bs + 2048 + wv * 512;

  const int arow = lane & 15;
  const int kcol = (lane >> 4) * 8;

  for (int k0 = 0; k0 < K; k0 += 32) {
    gllds16(ga0 + k0, la0);
    gllds16(ga1 + k0, la1);
    gllds16(gb0 + k0, lb0);
    gllds16(gb1 + k0, lb1);
    __syncthreads();
    bf16x8 af[4], bfr[4];
#pragma unroll
    for (int mi = 0; mi < 4; ++mi)
      af[mi] = *(const bf16x8*)(As + (wr + mi * 16 + arow) * 32 + kcol);
#pragma unroll
    for (int ni = 0; ni < 4; ++ni)
      bfr[ni] = *(const bf16x8*)(Bs + (wc + ni * 16 + arow) * 32 + kcol);
#pragma unroll
    for (int mi = 0; mi < 4; ++mi)
#pragma unroll
      for (int ni = 0; ni < 4; ++ni)
        acc[mi][ni] = __builtin_amdgcn_mfma_f32_16x16x32_bf16(af[mi], bfr[ni], acc[mi][ni], 0, 0, 0);
    __syncthreads();
  }

  const int crow = (lane >> 4) * 4;
  const int ccol = lane & 15;
#pragma unroll
  for (int mi = 0; mi < 4; ++mi) {
#pragma unroll
    for (int r = 0; r < 4; ++r) {
      int row = bm + wr + mi * 16 + crow + r;
      if (row < M) {
        if constexpr (BF16OUT) {
          u16* cp = (u16*)Cv + (size_t)row * Nn + bn + wc + ccol;
#pragma unroll
          for (int ni = 0; ni < 4; ++ni) cp[ni * 16] = f2bf(acc[mi][ni][r]);
        } else {
          float* cp = (float*)Cv + (size_t)row * Nn + bn + wc + ccol;
#pragma unroll
          for (int ni = 0; ni < 4; ++ni) cp[ni * 16] = acc[mi][ni][r];
        }
      }
    }
  }
}

// ---------- h2 = h1 @ W2 via split-bf16 MFMA (hi/lo 3-product, ~f32 accuracy) ----------
__global__ __launch_bounds__(256) void k_h2m(const u16* __restrict__ Ahi,
                                             const u16* __restrict__ Alo,
                                             const u16* __restrict__ Bhig,
                                             const u16* __restrict__ Blog,
                                             float* __restrict__ C, int M) {
  __shared__ u16 Bh[32 * 520];   // padded row stride 520: 2-way bank aliasing only
  __shared__ u16 Bl[32 * 520];
  const int tid = threadIdx.x, lane = tid & 63, wv = tid >> 6;
  for (int idx = tid; idx < 2048; idx += 256) {
    int e = idx * 8;
    int row = e >> 9, k = e & 511;
    *(u16x8*)(Bh + row * 520 + k) = *(const u16x8*)(Bhig + e);
    *(u16x8*)(Bl + row * 520 + k) = *(const u16x8*)(Blog + e);
  }
  __syncthreads();

  const int bm = blockIdx.x * 256 + wv * 64;
  const int arow = lane & 15, koff = (lane >> 4) * 8;

  f32x4 acc[4][2];
#pragma unroll
  for (int mi = 0; mi < 4; ++mi)
#pragma unroll
    for (int ni = 0; ni < 2; ++ni) acc[mi][ni] = (f32x4){0.f, 0.f, 0.f, 0.f};

  const u16* pah[4]; const u16* pal[4];
#pragma unroll
  for (int mi = 0; mi < 4; ++mi) {
    int r = bm + mi * 16 + arow; if (r >= M) r = M - 1;
    pah[mi] = Ahi + (size_t)r * DIM_HID + koff;
    pal[mi] = Alo + (size_t)r * DIM_HID + koff;
  }
  const u16* pbh[2]; const u16* pbl[2];
#pragma unroll
  for (int ni = 0; ni < 2; ++ni) {
    pbh[ni] = Bh + (ni * 16 + arow) * 520 + koff;
    pbl[ni] = Bl + (ni * 16 + arow) * 520 + koff;
  }

#pragma unroll
  for (int kk = 0; kk < 16; ++kk) {
    const int k0 = kk * 32;
    bf16x8 ah[4], al[4], bh[2], bl[2];
#pragma unroll
    for (int mi = 0; mi < 4; ++mi) {
      ah[mi] = *(const bf16x8*)(pah[mi] + k0);
      al[mi] = *(const bf16x8*)(pal[mi] + k0);
    }
#pragma unroll
    for (int ni = 0; ni < 2; ++ni) {
      bh[ni] = *(const bf16x8*)(pbh[ni] + k0);
      bl[ni] = *(const bf16x8*)(pbl[ni] + k0);
    }
#pragma unroll
    for (int mi = 0; mi < 4; ++mi)
#pragma unroll
      for (int ni = 0; ni < 2; ++ni) {
        acc[mi][ni] = __builtin_amdgcn_mfma_f32_16x16x32_bf16(ah[mi], bh[ni], acc[mi][ni], 0, 0, 0);
        acc[mi][ni] = __builtin_amdgcn_mfma_f32_16x16x32_bf16(al[mi], bh[ni], acc[mi][ni], 0, 0, 0);
        acc[mi][ni] = __builtin_amdgcn_mfma_f32_16x16x32_bf16(ah[mi], bl[ni], acc[mi][ni], 0, 0, 0);
      }
  }

  const int crow = (lane >> 4) * 4, ccol = lane & 15;
#pragma unroll
  for (int mi = 0; mi < 4; ++mi) {
#pragma unroll
    for (int r = 0; r < 4; ++r) {
      int row = bm + mi * 16 + crow + r;
      if (row < M) {
#pragma unroll
        for (int ni = 0; ni < 2; ++ni) {
          int col = ni * 16 + ccol;
          if (col < DIM_OUT) C[(size_t)row * DIM_OUT + col] = acc[mi][ni][r];
        }
      }
    }
  }
}

// ---------- CSR build ----------
__global__ void k_hist(const int* __restrict__ dst, int* __restrict__ counts, int E) {
  int i = blockIdx.x * blockDim.x + threadIdx.x;
  if (i < E) atomicAdd(&counts[dst[i]], 1);
}

__global__ void k_scan1(const int* __restrict__ counts, int* __restrict__ offs,
                        int* __restrict__ bsums, int n) {
  __shared__ int s[256];
  int i = blockIdx.x * 256 + threadIdx.x;
  int v = (i < n) ? counts[i] : 0;
  s[threadIdx.x] = v;
  __syncthreads();
  for (int d = 1; d < 256; d <<= 1) {
    int t = (threadIdx.x >= d) ? s[threadIdx.x - d] : 0;
    __syncthreads();
    s[threadIdx.x] += t;
    __syncthreads();
  }
  if (i < n) offs[i] = s[threadIdx.x] - v;          // block-local exclusive
  if (threadIdx.x == 255) bsums[blockIdx.x] = s[255];
}

__global__ void k_scan2(int* __restrict__ bsums, int nb) {
  __shared__ int s[256];
  int v = (threadIdx.x < nb) ? bsums[threadIdx.x] : 0;
  s[threadIdx.x] = v;
  __syncthreads();
  for (int d = 1; d < 256; d <<= 1) {
    int t = (threadIdx.x >= d) ? s[threadIdx.x - d] : 0;
    __syncthreads();
    s[threadIdx.x] += t;
    __syncthreads();
  }
  if (threadIdx.x < nb) bsums[threadIdx.x] = s[threadIdx.x] - v;  // exclusive
}

__global__ void k_scan3(int* __restrict__ offs, const int* __restrict__ bsums,
                        int* __restrict__ cursor, int n) {
  int i = blockIdx.x * 256 + threadIdx.x;
  if (i < n) {
    int o = offs[i] + bsums[blockIdx.x];
    offs[i] = o;
    cursor[i] = o;
  }
}

__global__ void k_fill(const int* __restrict__ dst, int* __restrict__ cursor,
                       int* __restrict__ eids, int E) {
  int i = blockIdx.x * blockDim.x + threadIdx.x;
  if (i < E) {
    int p = atomicAdd(&cursor[dst[i]], 1);
    eids[p] = i;
  }
}

// ---------- conv1 FUSED: bf16 h gather, online-softmax aggregation ----------
// h stored bf16 (halves the 614MB random gather). Score+aggregate in f32.
// Emits h1 as split bf16 (hi + lo) for the MFMA h2 GEMM.
__global__ __launch_bounds__(256) void k_conv1(
    const u16* __restrict__ hb, const int* __restrict__ src,
    const float* __restrict__ att, const int* __restrict__ offs,
    const int* __restrict__ cnts, const int* __restrict__ eids,
    float* __restrict__ alpha, u16* __restrict__ h1hi, u16* __restrict__ h1lo, int nN) {
  const int lane = threadIdx.x & 63, wv = threadIdx.x >> 6;
  const int nw = gridDim.x * 4;
  for (int v = blockIdx.x * 4 + wv; v < nN; v += nw) {
    const int col = lane * 8;
    u16x8 hd8 = *(const u16x8*)(hb + (size_t)v * DIM_HID + col);
    float hd[8];
#pragma unroll
    for (int i = 0; i < 8; ++i) hd[i] = bf2f(hd8[i]);
    float4 at0 = *(const float4*)(att + col), at1 = *(const float4*)(att + col + 4);
    float at[8] = { at0.x, at0.y, at0.z, at0.w, at1.x, at1.y, at1.z, at1.w };
    const int o = offs[v], deg = cnts[v];
    float m = -1e30f, den = 0.f;
    float c[8] = {0.f,0.f,0.f,0.f,0.f,0.f,0.f,0.f};
    u16x8 a8 = {0,0,0,0,0,0,0,0};
    if (deg > 0)
      a8 = *(const u16x8*)(hb + (size_t)src[eids[o]] * DIM_HID + col);
    for (int j = 0; j < deg; ++j) {
      u16x8 b8 = a8;
      if (j + 1 < deg)   // prefetch next edge while computing this one
        a8 = *(const u16x8*)(hb + (size_t)src[eids[o + j + 1]] * DIM_HID + col);
      float bs[8];
#pragma unroll
      for (int i = 0; i < 8; ++i) bs[i] = bf2f(b8[i]);
      float p = 0.f;
#pragma unroll
      for (int i = 0; i < 8; ++i) p += at[i] * lrelu(hd[i] + bs[i]);
#pragma unroll
      for (int msk = 1; msk < 64; msk <<= 1) p += __shfl_xor(p, msk, 64);
      if (lane == 0) alpha[o + j] = p;       // raw score, finalized below
      float mn = fmaxf(m, p);
      float sc = __expf(m - mn), w = __expf(p - mn);
      den = den * sc + w;
#pragma unroll
      for (int i = 0; i < 8; ++i) c[i] = c[i] * sc + w * bs[i];
      m = mn;
    }
    const float inv = (deg > 0) ? 1.f / den : 0.f;
    u16x8 hi8, lo8;
#pragma unroll
    for (int i = 0; i < 8; ++i) {
      float rv = elu(c[i] * inv);
      u16 hbv = f2bf(rv);
      hi8[i] = hbv;
      lo8[i] = f2bf(rv - bf2f(hbv));
    }
    *(u16x8*)(h1hi + (size_t)v * DIM_HID + col) = hi8;
    *(u16x8*)(h1lo + (size_t)v * DIM_HID + col) = lo8;
    // finalize alpha: scalar per edge, lane-parallel
    for (int j = lane; j < deg; j += 64)
      alpha[o + j] = __expf(alpha[o + j] - m) * inv;
  }
}

// ---------- conv3 aggregation in 30-dim space ----------
__global__ __launch_bounds__(256) void k_agg30(
    const float* __restrict__ h2, const int* __restrict__ src,
    const int* __restrict__ offs, const int* __restrict__ cnts,
    const int* __restrict__ eids, const float* __restrict__ alpha,
    float* __restrict__ agg30, int nN) {
  int gt = blockIdx.x * 256 + threadIdx.x;
  int v = gt >> 5, d = gt & 31;
  if (v >= nN || d >= DIM_OUT) return;
  const int o = offs[v], deg = cnts[v];
  float acc = 0.f;
  for (int j = 0; j < deg; ++j) {
    const int s = src[eids[o + j]];        // broadcast within half-wave
    acc += alpha[o + j] * h2[(size_t)s * DIM_OUT + d];
  }
  agg30[(size_t)v * DIM_OUT + d] = acc;
}

// ---------- h3 = elu(agg30 @ W2^T) -> bf16  ([N,30]x[30,512]) ----------
__global__ __launch_bounds__(256) void k_g3(const float* __restrict__ agg30,
                                            const float* __restrict__ W2,
                                            u16* __restrict__ h3b, int nN) {
  __shared__ float W2s[DIM_HID * 31];
  for (int i = threadIdx.x; i < DIM_HID * DIM_OUT; i += 256) {
    int k = i / DIM_OUT, c = i - k * DIM_OUT;
    W2s[k * 31 + c] = W2[i];
  }
  __syncthreads();
  const int lane = threadIdx.x & 63, wv = threadIdx.x >> 6;
  const int nw = gridDim.x * 4;
  for (int r = blockIdx.x * 4 + wv; r < nN; r += nw) {
    float hv[DIM_OUT];
    const float* hp = agg30 + (size_t)r * DIM_OUT;
#pragma unroll
    for (int c = 0; c < DIM_OUT; ++c) hv[c] = hp[c];
#pragma unroll
    for (int t = 0; t < 8; ++t) {
      int n = lane + t * 64;
      const float* w = W2s + n * 31;
      float a = 0.f;
#pragma unroll
      for (int c = 0; c < DIM_OUT; ++c) a += hv[c] * w[c];
      h3b[(size_t)r * DIM_HID + n] = f2bf(elu(a));
    }
  }
}

extern "C" void kernel_launch(void* const* d_in, const int* in_sizes, int n_in,
                              void* d_out, int out_size, void* d_ws, size_t ws_size,
                              hipStream_t stream) {
  const float* features = (const float*)d_in[0];
  const int*   eidx     = (const int*)d_in[1];
  const float* W1       = (const float*)d_in[2];
  const float* att1     = (const float*)d_in[3];
  const float* W2       = (const float*)d_in[4];
  const float* W4       = (const float*)d_in[5];
  const int* srcI = eidx;
  const int* dstI = eidx + N_EDGES;
  float* out = (float*)d_out;

  char* ws = (char*)d_ws;
  size_t off = 0;
  auto alloc = [&](size_t b) -> void* {
    void* p = ws + off;
    off += (b + 255) & ~(size_t)255;
    return p;
  };
  u16*   Xb     = (u16*)  alloc((size_t)N_NODES * DIM_IN * 2);   // later reused as h3 bf16
  u16*   W1T    = (u16*)  alloc((size_t)DIM_HID * DIM_IN * 2);
  u16*   W4T    = (u16*)  alloc((size_t)DIM_IN * DIM_HID * 2);
  u16*   hb     = (u16*)  alloc((size_t)N_NODES * DIM_HID * 2);  // h in bf16
  u16*   h1hi   = (u16*)  alloc((size_t)N_NODES * DIM_HID * 2);
  u16*   h1lo   = (u16*)  alloc((size_t)N_NODES * DIM_HID * 2);
  u16*   W2Thi  = (u16*)  alloc((size_t)32 * DIM_HID * 2);
  u16*   W2Tlo  = (u16*)  alloc((size_t)32 * DIM_HID * 2);
  int*   counts = (int*)  alloc((size_t)N_NODES * 4);
  int*   offs   = (int*)  alloc((size_t)N_NODES * 4);
  int*   cursor = (int*)  alloc((size_t)N_NODES * 4);
  int*   bsums  = (int*)  alloc(1024);
  int*   eids   = (int*)  alloc((size_t)N_EDGES * 4);
  float* alpha  = (float*)alloc((size_t)N_EDGES * 4);
  float* agg30  = (float*)alloc((size_t)N_NODES * DIM_OUT * 4);
  u16*   h3b    = Xb;

  // 1. convert inputs to bf16 (+ transposed weights for MFMA B-operand)
  k_cvt<<<(N_NODES * DIM_IN / 4 + 255) / 256, 256, 0, stream>>>(features, Xb, N_NODES * DIM_IN / 4);
  k_transpose<<<dim3(DIM_IN / 256, DIM_HID), 256, 0, stream>>>(W1, W1T, DIM_IN, DIM_HID);
  k_transpose<<<dim3(DIM_HID / 256, DIM_IN), 256, 0, stream>>>(W4, W4T, DIM_HID, DIM_IN);
  k_w2t<<<(32 * DIM_HID + 255) / 256, 256, 0, stream>>>(W2, W2Thi, W2Tlo);

  // 2. h = X @ W1  (bf16 out: conv1's gather operand)
  k_gemm<true><<<dim3((N_NODES + 127) / 128, DIM_HID / 128), 256, 0, stream>>>(
      Xb, W1T, hb, N_NODES, DIM_HID, DIM_IN);

  // 3. CSR by dst
  hipMemsetAsync(counts, 0, (size_t)N_NODES * 4, stream);
  k_hist<<<(N_EDGES + 255) / 256, 256, 0, stream>>>(dstI, counts, N_EDGES);
  const int nScanBlocks = (N_NODES + 255) / 256;  // 196
  k_scan1<<<nScanBlocks, 256, 0, stream>>>(counts, offs, bsums, N_NODES);
  k_scan2<<<1, 256, 0, stream>>>(bsums, nScanBlocks);
  k_scan3<<<nScanBlocks, 256, 0, stream>>>(offs, bsums, cursor, N_NODES);
  k_fill<<<(N_EDGES + 255) / 256, 256, 0, stream>>>(dstI, cursor, eids, N_EDGES);

  // 4. conv1 fused: scores + online softmax + aggregate + ELU (one bf16 gather pass)
  k_conv1<<<N_NODES / 4, 256, 0, stream>>>(hb, srcI, att1, offs, counts, eids, alpha,
                                           h1hi, h1lo, N_NODES);

  // 5. h2 = h1 @ W2 -> out[0 : N*30) via split-bf16 MFMA
  k_h2m<<<(N_NODES + 255) / 256, 256, 0, stream>>>(h1hi, h1lo, W2Thi, W2Tlo, out, N_NODES);

  // 6. conv3 aggregation in 30-dim space (linearity of aggregate over W2^T)
  k_agg30<<<(N_NODES * 32 + 255) / 256, 256, 0, stream>>>(
      out, srcI, offs, counts, eids, alpha, agg30, N_NODES);

  // 7. h3 = elu(agg30 @ W2^T) -> bf16 (aliases Xb)
  k_g3<<<1024, 256, 0, stream>>>(agg30, W2, h3b, N_NODES);

  // 8. h4 = h3 @ W4 -> out[N*30 : )
  k_gemm<false><<<dim3((N_NODES + 127) / 128, DIM_IN / 128), 256, 0, stream>>>(
      h3b, W4T, out + (size_t)N_NODES * DIM_OUT, N_NODES, DIM_IN, DIM_HID);
}

// Round 4
// 796.174 us; speedup vs baseline: 1.2273x; 1.0151x over previous
//
#include <hip/hip_runtime.h>
#include <stdint.h>

#define N_NODES 50000
#define N_EDGES 300000
#define DIM_IN  1024
#define DIM_HID 512
#define DIM_OUT 30

typedef unsigned short u16;
typedef __bf16 bf16x8 __attribute__((ext_vector_type(8)));
typedef float  f32x4  __attribute__((ext_vector_type(4)));
typedef u16    u16x4  __attribute__((ext_vector_type(4)));
typedef u16    u16x8  __attribute__((ext_vector_type(8)));

typedef __attribute__((address_space(3))) uint32_t lds_u32;
typedef __attribute__((address_space(1))) uint32_t gl_u32;

__device__ __forceinline__ void gllds16(const u16* g, u16* l) {
  // async global->LDS, 16B/lane; LDS dest = wave-uniform base + lane*16
  __builtin_amdgcn_global_load_lds((const gl_u32*)g, (lds_u32*)l, 16, 0, 0);
}

__device__ __forceinline__ float lrelu(float x) { return x > 0.f ? x : 0.2f * x; }
__device__ __forceinline__ float elu(float x)   { return x > 0.f ? x : __expf(x) - 1.f; }
__device__ __forceinline__ u16 f2bf(float x) {
  uint32_t u = __float_as_uint(x);
  u += 0x7fffu + ((u >> 16) & 1u);   // round-to-nearest-even
  return (u16)(u >> 16);
}
__device__ __forceinline__ float bf2f(u16 b) {
  return __uint_as_float((uint32_t)b << 16);
}

// ---------- transpose + convert: in[R][C] f32 -> out[C][R] bf16 ----------
__global__ void k_transpose(const float* __restrict__ in, u16* __restrict__ out, int R, int C) {
  int r = blockIdx.x * 256 + threadIdx.x;
  int c = blockIdx.y;
  if (r < R) out[(size_t)c * R + r] = f2bf(in[(size_t)r * C + c]);
}

// ---------- W2 [512][30] f32 -> W2T hi/lo bf16 [32][512] (rows 30,31 zero) ----------
__global__ void k_w2t(const float* __restrict__ W2, u16* __restrict__ hiT, u16* __restrict__ loT) {
  int i = blockIdx.x * 256 + threadIdx.x;
  if (i >= 32 * 512) return;
  int c = i >> 9, k = i & 511;                  // c = out row (col of W2), k
  float v = (c < DIM_OUT) ? W2[(size_t)k * DIM_OUT + c] : 0.f;
  u16 hb = f2bf(v);
  hiT[i] = hb;
  loT[i] = f2bf(v - bf2f(hb));
}

// ---------- fused cvt+GEMM: C_bf16[M][Nn] = f32 A[M][K] * bf16 BT[Nn][K]^T ----------
// A staged via reg (f32 load -> RTNE cvt -> ds_write_b128); B via global_load_lds.
// Kills the separate 307MB k_cvt pass.
__global__ __launch_bounds__(256) void k_gemm_xw1(const float* __restrict__ A,
                                                  const u16* __restrict__ BT,
                                                  u16* __restrict__ Cb,
                                                  int M, int Nn, int K) {
  __shared__ u16 As[128 * 32];
  __shared__ u16 Bs[128 * 32];
  const int tid  = threadIdx.x;
  const int lane = tid & 63;
  const int wv   = tid >> 6;
  const int bm = blockIdx.x * 128;
  const int bn = blockIdx.y * 128;
  const int wr = (wv >> 1) * 64;
  const int wc = (wv & 1) * 64;
  const int r0 = tid >> 2;          // 0..63
  const int c0 = (tid & 3) * 8;     // 0,8,16,24 (elements)

  f32x4 acc[4][4];
#pragma unroll
  for (int i = 0; i < 4; ++i)
#pragma unroll
    for (int j = 0; j < 4; ++j) acc[i][j] = (f32x4){0.f, 0.f, 0.f, 0.f};

  int ra = bm + r0;      if (ra >= M) ra = M - 1;
  int rb = bm + r0 + 64; if (rb >= M) rb = M - 1;
  const float* ga0 = A + (size_t)ra * K + c0;
  const float* ga1 = A + (size_t)rb * K + c0;
  const u16* gb0 = BT + (size_t)(bn + r0) * K + c0;
  const u16* gb1 = BT + (size_t)(bn + r0 + 64) * K + c0;
  u16* lb0 = Bs + wv * 512;
  u16* lb1 = Bs + 2048 + wv * 512;

  const int arow = lane & 15;
  const int kcol = (lane >> 4) * 8;

  for (int k0 = 0; k0 < K; k0 += 32) {
    // B: async direct-to-LDS
    gllds16(gb0 + k0, lb0);
    gllds16(gb1 + k0, lb1);
    // A: f32 -> regs -> bf16 -> LDS (elem offset tid*8 == row-major [128][32])
    float4 fa0 = *(const float4*)(ga0 + k0);
    float4 fa1 = *(const float4*)(ga0 + k0 + 4);
    float4 fb0 = *(const float4*)(ga1 + k0);
    float4 fb1 = *(const float4*)(ga1 + k0 + 4);
    bf16x8 w0, w1;
    w0[0] = (__bf16)fa0.x; w0[1] = (__bf16)fa0.y; w0[2] = (__bf16)fa0.z; w0[3] = (__bf16)fa0.w;
    w0[4] = (__bf16)fa1.x; w0[5] = (__bf16)fa1.y; w0[6] = (__bf16)fa1.z; w0[7] = (__bf16)fa1.w;
    w1[0] = (__bf16)fb0.x; w1[1] = (__bf16)fb0.y; w1[2] = (__bf16)fb0.z; w1[3] = (__bf16)fb0.w;
    w1[4] = (__bf16)fb1.x; w1[5] = (__bf16)fb1.y; w1[6] = (__bf16)fb1.z; w1[7] = (__bf16)fb1.w;
    *(bf16x8*)(As + tid * 8)        = w0;
    *(bf16x8*)(As + 2048 + tid * 8) = w1;
    __syncthreads();
    bf16x8 af[4], bfr[4];
#pragma unroll
    for (int mi = 0; mi < 4; ++mi)
      af[mi] = *(const bf16x8*)(As + (wr + mi * 16 + arow) * 32 + kcol);
#pragma unroll
    for (int ni = 0; ni < 4; ++ni)
      bfr[ni] = *(const bf16x8*)(Bs + (wc + ni * 16 + arow) * 32 + kcol);
#pragma unroll
    for (int mi = 0; mi < 4; ++mi)
#pragma unroll
      for (int ni = 0; ni < 4; ++ni)
        acc[mi][ni] = __builtin_amdgcn_mfma_f32_16x16x32_bf16(af[mi], bfr[ni], acc[mi][ni], 0, 0, 0);
    __syncthreads();
  }

  const int crow = (lane >> 4) * 4;
  const int ccol = lane & 15;
#pragma unroll
  for (int mi = 0; mi < 4; ++mi) {
#pragma unroll
    for (int r = 0; r < 4; ++r) {
      int row = bm + wr + mi * 16 + crow + r;
      if (row < M) {
        u16* cp = Cb + (size_t)row * Nn + bn + wc + ccol;
#pragma unroll
        for (int ni = 0; ni < 4; ++ni) cp[ni * 16] = f2bf(acc[mi][ni][r]);
      }
    }
  }
}

// ---------- bf16 MFMA GEMM: C[M][Nn] = A[M][K] * BT[Nn][K]^T (f32 out) ----------
__global__ __launch_bounds__(256) void k_gemm(const u16* __restrict__ A,
                                              const u16* __restrict__ BT,
                                              float* __restrict__ C,
                                              int M, int Nn, int K) {
  __shared__ u16 As[128 * 32];
  __shared__ u16 Bs[128 * 32];
  const int tid  = threadIdx.x;
  const int lane = tid & 63;
  const int wv   = tid >> 6;
  const int bm = blockIdx.x * 128;
  const int bn = blockIdx.y * 128;
  const int wr = (wv >> 1) * 64;
  const int wc = (wv & 1) * 64;
  const int r0 = tid >> 2;          // 0..63
  const int c0 = (tid & 3) * 8;     // 0,8,16,24 (elements)

  f32x4 acc[4][4];
#pragma unroll
  for (int i = 0; i < 4; ++i)
#pragma unroll
    for (int j = 0; j < 4; ++j) acc[i][j] = (f32x4){0.f, 0.f, 0.f, 0.f};

  int ra = bm + r0;      if (ra >= M) ra = M - 1;
  int rb = bm + r0 + 64; if (rb >= M) rb = M - 1;
  const u16* ga0 = A  + (size_t)ra * K + c0;
  const u16* ga1 = A  + (size_t)rb * K + c0;
  const u16* gb0 = BT + (size_t)(bn + r0) * K + c0;
  const u16* gb1 = BT + (size_t)(bn + r0 + 64) * K + c0;
  u16* la0 = As + wv * 512;
  u16* la1 = As + 2048 + wv * 512;
  u16* lb0 = Bs + wv * 512;
  u16* lb1 = Bs + 2048 + wv * 512;

  const int arow = lane & 15;
  const int kcol = (lane >> 4) * 8;

  for (int k0 = 0; k0 < K; k0 += 32) {
    gllds16(ga0 + k0, la0);
    gllds16(ga1 + k0, la1);
    gllds16(gb0 + k0, lb0);
    gllds16(gb1 + k0, lb1);
    __syncthreads();
    bf16x8 af[4], bfr[4];
#pragma unroll
    for (int mi = 0; mi < 4; ++mi)
      af[mi] = *(const bf16x8*)(As + (wr + mi * 16 + arow) * 32 + kcol);
#pragma unroll
    for (int ni = 0; ni < 4; ++ni)
      bfr[ni] = *(const bf16x8*)(Bs + (wc + ni * 16 + arow) * 32 + kcol);
#pragma unroll
    for (int mi = 0; mi < 4; ++mi)
#pragma unroll
      for (int ni = 0; ni < 4; ++ni)
        acc[mi][ni] = __builtin_amdgcn_mfma_f32_16x16x32_bf16(af[mi], bfr[ni], acc[mi][ni], 0, 0, 0);
    __syncthreads();
  }

  const int crow = (lane >> 4) * 4;
  const int ccol = lane & 15;
#pragma unroll
  for (int mi = 0; mi < 4; ++mi) {
#pragma unroll
    for (int r = 0; r < 4; ++r) {
      int row = bm + wr + mi * 16 + crow + r;
      if (row < M) {
        float* cp = C + (size_t)row * Nn + bn + wc + ccol;
#pragma unroll
        for (int ni = 0; ni < 4; ++ni) cp[ni * 16] = acc[mi][ni][r];
      }
    }
  }
}

// ---------- h2 = h1 @ W2 via split-bf16 MFMA (hi/lo 3-product, ~f32 accuracy) ----------
__global__ __launch_bounds__(256) void k_h2m(const u16* __restrict__ Ahi,
                                             const u16* __restrict__ Alo,
                                             const u16* __restrict__ Bhig,
                                             const u16* __restrict__ Blog,
                                             float* __restrict__ C, int M) {
  __shared__ u16 Bh[32 * 520];   // padded row stride 520: 2-way bank aliasing only
  __shared__ u16 Bl[32 * 520];
  const int tid = threadIdx.x, lane = tid & 63, wv = tid >> 6;
  for (int idx = tid; idx < 2048; idx += 256) {
    int e = idx * 8;
    int row = e >> 9, k = e & 511;
    *(u16x8*)(Bh + row * 520 + k) = *(const u16x8*)(Bhig + e);
    *(u16x8*)(Bl + row * 520 + k) = *(const u16x8*)(Blog + e);
  }
  __syncthreads();

  const int bm = blockIdx.x * 256 + wv * 64;
  const int arow = lane & 15, koff = (lane >> 4) * 8;

  f32x4 acc[4][2];
#pragma unroll
  for (int mi = 0; mi < 4; ++mi)
#pragma unroll
    for (int ni = 0; ni < 2; ++ni) acc[mi][ni] = (f32x4){0.f, 0.f, 0.f, 0.f};

  const u16* pah[4]; const u16* pal[4];
#pragma unroll
  for (int mi = 0; mi < 4; ++mi) {
    int r = bm + mi * 16 + arow; if (r >= M) r = M - 1;
    pah[mi] = Ahi + (size_t)r * DIM_HID + koff;
    pal[mi] = Alo + (size_t)r * DIM_HID + koff;
  }
  const u16* pbh[2]; const u16* pbl[2];
#pragma unroll
  for (int ni = 0; ni < 2; ++ni) {
    pbh[ni] = Bh + (ni * 16 + arow) * 520 + koff;
    pbl[ni] = Bl + (ni * 16 + arow) * 520 + koff;
  }

#pragma unroll
  for (int kk = 0; kk < 16; ++kk) {
    const int k0 = kk * 32;
    bf16x8 ah[4], al[4], bh[2], bl[2];
#pragma unroll
    for (int mi = 0; mi < 4; ++mi) {
      ah[mi] = *(const bf16x8*)(pah[mi] + k0);
      al[mi] = *(const bf16x8*)(pal[mi] + k0);
    }
#pragma unroll
    for (int ni = 0; ni < 2; ++ni) {
      bh[ni] = *(const bf16x8*)(pbh[ni] + k0);
      bl[ni] = *(const bf16x8*)(pbl[ni] + k0);
    }
#pragma unroll
    for (int mi = 0; mi < 4; ++mi)
#pragma unroll
      for (int ni = 0; ni < 2; ++ni) {
        acc[mi][ni] = __builtin_amdgcn_mfma_f32_16x16x32_bf16(ah[mi], bh[ni], acc[mi][ni], 0, 0, 0);
        acc[mi][ni] = __builtin_amdgcn_mfma_f32_16x16x32_bf16(al[mi], bh[ni], acc[mi][ni], 0, 0, 0);
        acc[mi][ni] = __builtin_amdgcn_mfma_f32_16x16x32_bf16(ah[mi], bl[ni], acc[mi][ni], 0, 0, 0);
      }
  }

  const int crow = (lane >> 4) * 4, ccol = lane & 15;
#pragma unroll
  for (int mi = 0; mi < 4; ++mi) {
#pragma unroll
    for (int r = 0; r < 4; ++r) {
      int row = bm + mi * 16 + crow + r;
      if (row < M) {
#pragma unroll
        for (int ni = 0; ni < 2; ++ni) {
          int col = ni * 16 + ccol;
          if (col < DIM_OUT) C[(size_t)row * DIM_OUT + col] = acc[mi][ni][r];
        }
      }
    }
  }
}

// ---------- CSR build ----------
__global__ void k_hist(const int* __restrict__ dst, int* __restrict__ counts, int E) {
  int i = blockIdx.x * blockDim.x + threadIdx.x;
  if (i < E) atomicAdd(&counts[dst[i]], 1);
}

__global__ void k_scan1(const int* __restrict__ counts, int* __restrict__ offs,
                        int* __restrict__ bsums, int n) {
  __shared__ int s[256];
  int i = blockIdx.x * 256 + threadIdx.x;
  int v = (i < n) ? counts[i] : 0;
  s[threadIdx.x] = v;
  __syncthreads();
  for (int d = 1; d < 256; d <<= 1) {
    int t = (threadIdx.x >= d) ? s[threadIdx.x - d] : 0;
    __syncthreads();
    s[threadIdx.x] += t;
    __syncthreads();
  }
  if (i < n) offs[i] = s[threadIdx.x] - v;          // block-local exclusive
  if (threadIdx.x == 255) bsums[blockIdx.x] = s[255];
}

__global__ void k_scan2(int* __restrict__ bsums, int nb) {
  __shared__ int s[256];
  int v = (threadIdx.x < nb) ? bsums[threadIdx.x] : 0;
  s[threadIdx.x] = v;
  __syncthreads();
  for (int d = 1; d < 256; d <<= 1) {
    int t = (threadIdx.x >= d) ? s[threadIdx.x - d] : 0;
    __syncthreads();
    s[threadIdx.x] += t;
    __syncthreads();
  }
  if (threadIdx.x < nb) bsums[threadIdx.x] = s[threadIdx.x] - v;  // exclusive
}

__global__ void k_scan3(int* __restrict__ offs, const int* __restrict__ bsums,
                        int* __restrict__ cursor, int n) {
  int i = blockIdx.x * 256 + threadIdx.x;
  if (i < n) {
    int o = offs[i] + bsums[blockIdx.x];
    offs[i] = o;
    cursor[i] = o;
  }
}

__global__ void k_fill(const int* __restrict__ dst, int* __restrict__ cursor,
                       int* __restrict__ eids, int E) {
  int i = blockIdx.x * blockDim.x + threadIdx.x;
  if (i < E) {
    int p = atomicAdd(&cursor[dst[i]], 1);
    eids[p] = i;
  }
}

// ---------- conv1 FUSED: bf16 h gather, online-softmax aggregation ----------
// Edge indices fetched in PARALLEL across lanes (breaks the eids->src->row serial
// chain), broadcast via shfl; 2-deep row prefetch. Emits h1 as split hi/lo bf16.
__global__ __launch_bounds__(256) void k_conv1(
    const u16* __restrict__ hb, const int* __restrict__ src,
    const float* __restrict__ att, const int* __restrict__ offs,
    const int* __restrict__ cnts, const int* __restrict__ eids,
    float* __restrict__ alpha, u16* __restrict__ h1hi, u16* __restrict__ h1lo, int nN) {
  const int lane = threadIdx.x & 63, wv = threadIdx.x >> 6;
  const int nw = gridDim.x * 4;
  for (int v = blockIdx.x * 4 + wv; v < nN; v += nw) {
    const int col = lane * 8;
    u16x8 hd8 = *(const u16x8*)(hb + (size_t)v * DIM_HID + col);
    float hd[8];
#pragma unroll
    for (int i = 0; i < 8; ++i) hd[i] = bf2f(hd8[i]);
    float4 at0 = *(const float4*)(att + col), at1 = *(const float4*)(att + col + 4);
    float at[8] = { at0.x, at0.y, at0.z, at0.w, at1.x, at1.y, at1.z, at1.w };
    const int o = offs[v], deg = cnts[v];
    float m = -1e30f, den = 0.f;
    float c[8] = {0.f,0.f,0.f,0.f,0.f,0.f,0.f,0.f};
    for (int base = 0; base < deg; base += 64) {
      const int nchunk = min(deg - base, 64);
      int myeid = (lane < nchunk) ? eids[o + base + lane] : 0;
      int mysrc = src[myeid];                       // parallel index fetch
      u16x8 r0 = {0,0,0,0,0,0,0,0}, r1 = {0,0,0,0,0,0,0,0};
      int s = __shfl(mysrc, 0, 64);
      r0 = *(const u16x8*)(hb + (size_t)s * DIM_HID + col);
      if (nchunk > 1) {
        s = __shfl(mysrc, 1, 64);
        r1 = *(const u16x8*)(hb + (size_t)s * DIM_HID + col);
      }
      for (int j = 0; j < nchunk; ++j) {
        u16x8 b8 = r0;
        r0 = r1;
        if (j + 2 < nchunk) {                       // 2-deep prefetch
          s = __shfl(mysrc, j + 2, 64);
          r1 = *(const u16x8*)(hb + (size_t)s * DIM_HID + col);
        }
        float bs[8];
#pragma unroll
        for (int i = 0; i < 8; ++i) bs[i] = bf2f(b8[i]);
        float p = 0.f;
#pragma unroll
        for (int i = 0; i < 8; ++i) p += at[i] * lrelu(hd[i] + bs[i]);
#pragma unroll
        for (int msk = 1; msk < 64; msk <<= 1) p += __shfl_xor(p, msk, 64);
        if (lane == 0) alpha[o + base + j] = p;     // raw score, finalized below
        float mn = fmaxf(m, p);
        float sc = __expf(m - mn), w = __expf(p - mn);
        den = den * sc + w;
#pragma unroll
        for (int i = 0; i < 8; ++i) c[i] = c[i] * sc + w * bs[i];
        m = mn;
      }
    }
    const float inv = (deg > 0) ? 1.f / den : 0.f;
    u16x8 hi8, lo8;
#pragma unroll
    for (int i = 0; i < 8; ++i) {
      float rv = elu(c[i] * inv);
      u16 hbv = f2bf(rv);
      hi8[i] = hbv;
      lo8[i] = f2bf(rv - bf2f(hbv));
    }
    *(u16x8*)(h1hi + (size_t)v * DIM_HID + col) = hi8;
    *(u16x8*)(h1lo + (size_t)v * DIM_HID + col) = lo8;
    // finalize alpha: scalar per edge, lane-parallel
    for (int j = lane; j < deg; j += 64)
      alpha[o + j] = __expf(alpha[o + j] - m) * inv;
  }
}

// ---------- conv3 aggregation in 30-dim space ----------
// Half-wave per node; parallel (eid,src,alpha) fetch + shfl broadcast, 1-deep prefetch.
__global__ __launch_bounds__(256) void k_agg30(
    const float* __restrict__ h2, const int* __restrict__ src,
    const int* __restrict__ offs, const int* __restrict__ cnts,
    const int* __restrict__ eids, const float* __restrict__ alpha,
    float* __restrict__ agg30, int nN) {
  int gt = blockIdx.x * 256 + threadIdx.x;
  int v = gt >> 5, d = gt & 31;
  if (v >= nN) return;
  const int o = offs[v], deg = cnts[v];
  float acc = 0.f;
  for (int base = 0; base < deg; base += 32) {
    const int nchunk = min(deg - base, 32);
    int myeid = (d < nchunk) ? eids[o + base + d] : 0;
    int mysrc = src[myeid];
    float myal = (d < nchunk) ? alpha[o + base + d] : 0.f;
    int s = __shfl(mysrc, 0, 32);
    float pv = (d < DIM_OUT) ? h2[(size_t)s * DIM_OUT + d] : 0.f;
    for (int j = 0; j < nchunk; ++j) {
      float hv = pv;
      if (j + 1 < nchunk) {
        s = __shfl(mysrc, j + 1, 32);
        pv = (d < DIM_OUT) ? h2[(size_t)s * DIM_OUT + d] : 0.f;
      }
      acc += __shfl(myal, j, 32) * hv;
    }
  }
  if (d < DIM_OUT) agg30[(size_t)v * DIM_OUT + d] = acc;
}

// ---------- h3 = elu(agg30 @ W2^T) -> bf16  ([N,30]x[30,512]) ----------
__global__ __launch_bounds__(256) void k_g3(const float* __restrict__ agg30,
                                            const float* __restrict__ W2,
                                            u16* __restrict__ h3b, int nN) {
  __shared__ float W2s[DIM_HID * 31];
  for (int i = threadIdx.x; i < DIM_HID * DIM_OUT; i += 256) {
    int k = i / DIM_OUT, c = i - k * DIM_OUT;
    W2s[k * 31 + c] = W2[i];
  }
  __syncthreads();
  const int lane = threadIdx.x & 63, wv = threadIdx.x >> 6;
  const int nw = gridDim.x * 4;
  for (int r = blockIdx.x * 4 + wv; r < nN; r += nw) {
    float hv[DIM_OUT];
    const float* hp = agg30 + (size_t)r * DIM_OUT;
#pragma unroll
    for (int c = 0; c < DIM_OUT; ++c) hv[c] = hp[c];
#pragma unroll
    for (int t = 0; t < 8; ++t) {
      int n = lane + t * 64;
      const float* w = W2s + n * 31;
      float a = 0.f;
#pragma unroll
      for (int c = 0; c < DIM_OUT; ++c) a += hv[c] * w[c];
      h3b[(size_t)r * DIM_HID + n] = f2bf(elu(a));
    }
  }
}

extern "C" void kernel_launch(void* const* d_in, const int* in_sizes, int n_in,
                              void* d_out, int out_size, void* d_ws, size_t ws_size,
                              hipStream_t stream) {
  const float* features = (const float*)d_in[0];
  const int*   eidx     = (const int*)d_in[1];
  const float* W1       = (const float*)d_in[2];
  const float* att1     = (const float*)d_in[3];
  const float* W2       = (const float*)d_in[4];
  const float* W4       = (const float*)d_in[5];
  const int* srcI = eidx;
  const int* dstI = eidx + N_EDGES;
  float* out = (float*)d_out;

  char* ws = (char*)d_ws;
  size_t off = 0;
  auto alloc = [&](size_t b) -> void* {
    void* p = ws + off;
    off += (b + 255) & ~(size_t)255;
    return p;
  };
  u16*   W1T    = (u16*)  alloc((size_t)DIM_HID * DIM_IN * 2);
  u16*   W4T    = (u16*)  alloc((size_t)DIM_IN * DIM_HID * 2);
  u16*   hb     = (u16*)  alloc((size_t)N_NODES * DIM_HID * 2);  // h in bf16
  u16*   h1hi   = (u16*)  alloc((size_t)N_NODES * DIM_HID * 2);
  u16*   h1lo   = (u16*)  alloc((size_t)N_NODES * DIM_HID * 2);
  u16*   h3b    = (u16*)  alloc((size_t)N_NODES * DIM_HID * 2);
  u16*   W2Thi  = (u16*)  alloc((size_t)32 * DIM_HID * 2);
  u16*   W2Tlo  = (u16*)  alloc((size_t)32 * DIM_HID * 2);
  int*   counts = (int*)  alloc((size_t)N_NODES * 4);
  int*   offs   = (int*)  alloc((size_t)N_NODES * 4);
  int*   cursor = (int*)  alloc((size_t)N_NODES * 4);
  int*   bsums  = (int*)  alloc(1024);
  int*   eids   = (int*)  alloc((size_t)N_EDGES * 4);
  float* alpha  = (float*)alloc((size_t)N_EDGES * 4);
  float* agg30  = (float*)alloc((size_t)N_NODES * DIM_OUT * 4);

  // 1. transposed bf16 weights for MFMA B-operand (+ W2T hi/lo)
  k_transpose<<<dim3(DIM_IN / 256, DIM_HID), 256, 0, stream>>>(W1, W1T, DIM_IN, DIM_HID);
  k_transpose<<<dim3(DIM_HID / 256, DIM_IN), 256, 0, stream>>>(W4, W4T, DIM_HID, DIM_IN);
  k_w2t<<<(32 * DIM_HID + 255) / 256, 256, 0, stream>>>(W2, W2Thi, W2Tlo);

  // 2. h = X @ W1 (fused f32->bf16 A staging; bf16 out for conv1's gather)
  k_gemm_xw1<<<dim3((N_NODES + 127) / 128, DIM_HID / 128), 256, 0, stream>>>(
      features, W1T, hb, N_NODES, DIM_HID, DIM_IN);

  // 3. CSR by dst
  hipMemsetAsync(counts, 0, (size_t)N_NODES * 4, stream);
  k_hist<<<(N_EDGES + 255) / 256, 256, 0, stream>>>(dstI, counts, N_EDGES);
  const int nScanBlocks = (N_NODES + 255) / 256;  // 196
  k_scan1<<<nScanBlocks, 256, 0, stream>>>(counts, offs, bsums, N_NODES);
  k_scan2<<<1, 256, 0, stream>>>(bsums, nScanBlocks);
  k_scan3<<<nScanBlocks, 256, 0, stream>>>(offs, bsums, cursor, N_NODES);
  k_fill<<<(N_EDGES + 255) / 256, 256, 0, stream>>>(dstI, cursor, eids, N_EDGES);

  // 4. conv1 fused: scores + online softmax + aggregate + ELU (one bf16 gather pass)
  k_conv1<<<N_NODES / 4, 256, 0, stream>>>(hb, srcI, att1, offs, counts, eids, alpha,
                                           h1hi, h1lo, N_NODES);

  // 5. h2 = h1 @ W2 -> out[0 : N*30) via split-bf16 MFMA
  k_h2m<<<(N_NODES + 255) / 256, 256, 0, stream>>>(h1hi, h1lo, W2Thi, W2Tlo, out, N_NODES);

  // 6. conv3 aggregation in 30-dim space (linearity of aggregate over W2^T)
  k_agg30<<<(N_NODES * 32 + 255) / 256, 256, 0, stream>>>(
      out, srcI, offs, counts, eids, alpha, agg30, N_NODES);

  // 7. h3 = elu(agg30 @ W2^T) -> bf16
  k_g3<<<1024, 256, 0, stream>>>(agg30, W2, h3b, N_NODES);

  // 8. h4 = h3 @ W4 -> out[N*30 : )
  k_gemm<<<dim3((N_NODES + 127) / 128, DIM_IN / 128), 256, 0, stream>>>(
      h3b, W4T, out + (size_t)N_NODES * DIM_OUT, N_NODES, DIM_IN, DIM_HID);
}

// Round 5
// 763.893 us; speedup vs baseline: 1.2792x; 1.0423x over previous
//
#include <hip/hip_runtime.h>
#include <stdint.h>

#define N_NODES 50000
#define N_EDGES 300000
#define DIM_IN  1024
#define DIM_HID 512
#define DIM_OUT 30

typedef unsigned short u16;
typedef __bf16 bf16x8 __attribute__((ext_vector_type(8)));
typedef float  f32x4  __attribute__((ext_vector_type(4)));
typedef u16    u16x4  __attribute__((ext_vector_type(4)));
typedef u16    u16x8  __attribute__((ext_vector_type(8)));

typedef __attribute__((address_space(3))) uint32_t lds_u32;
typedef __attribute__((address_space(1))) uint32_t gl_u32;

__device__ __forceinline__ void gllds16(const u16* g, u16* l) {
  // async global->LDS, 16B/lane; LDS dest = wave-uniform base + lane*16
  __builtin_amdgcn_global_load_lds((const gl_u32*)g, (lds_u32*)l, 16, 0, 0);
}

__device__ __forceinline__ float lrelu(float x) { return x > 0.f ? x : 0.2f * x; }
__device__ __forceinline__ float elu(float x)   { return x > 0.f ? x : __expf(x) - 1.f; }
__device__ __forceinline__ u16 f2bf(float x) {
  uint32_t u = __float_as_uint(x);
  u += 0x7fffu + ((u >> 16) & 1u);   // round-to-nearest-even
  return (u16)(u >> 16);
}
__device__ __forceinline__ float bf2f(u16 b) {
  return __uint_as_float((uint32_t)b << 16);
}

// ---------- transpose + convert: in[R][C] f32 -> out[C][R] bf16 ----------
__global__ void k_transpose(const float* __restrict__ in, u16* __restrict__ out, int R, int C) {
  int r = blockIdx.x * 256 + threadIdx.x;
  int c = blockIdx.y;
  if (r < R) out[(size_t)c * R + r] = f2bf(in[(size_t)r * C + c]);
}

// ---------- W2 [512][30] f32 -> W2T hi/lo bf16 [32][512] (rows 30,31 zero) ----------
__global__ void k_w2t(const float* __restrict__ W2, u16* __restrict__ hiT, u16* __restrict__ loT) {
  int i = blockIdx.x * 256 + threadIdx.x;
  if (i >= 32 * 512) return;
  int c = i >> 9, k = i & 511;                  // c = out row (col of W2), k
  float v = (c < DIM_OUT) ? W2[(size_t)k * DIM_OUT + c] : 0.f;
  u16 hb = f2bf(v);
  hiT[i] = hb;
  loT[i] = f2bf(v - bf2f(hb));
}

// ---------- fused cvt+GEMM: C_bf16[M][Nn] = f32 A[M][K] * bf16 BT[Nn][K]^T ----------
// bn = blockIdx.x (FAST dim): consecutive blocks share the A row-panel -> A fetched
// from HBM once, not Nn/128 times. A staged via reg prefetch (f32 -> RTNE -> LDS).
__global__ __launch_bounds__(256) void k_gemm_xw1(const float* __restrict__ A,
                                                  const u16* __restrict__ BT,
                                                  u16* __restrict__ Cb,
                                                  int M, int Nn, int K) {
  __shared__ u16 As[128 * 32];
  __shared__ u16 Bs[128 * 32];
  const int tid  = threadIdx.x;
  const int lane = tid & 63;
  const int wv   = tid >> 6;
  const int bm = blockIdx.y * 128;   // slow dim
  const int bn = blockIdx.x * 128;   // fast dim: A-panel reuse across XCDs
  const int wr = (wv >> 1) * 64;
  const int wc = (wv & 1) * 64;
  const int r0 = tid >> 2;          // 0..63
  const int c0 = (tid & 3) * 8;     // 0,8,16,24 (elements)

  f32x4 acc[4][4];
#pragma unroll
  for (int i = 0; i < 4; ++i)
#pragma unroll
    for (int j = 0; j < 4; ++j) acc[i][j] = (f32x4){0.f, 0.f, 0.f, 0.f};

  int ra = bm + r0;      if (ra >= M) ra = M - 1;
  int rb = bm + r0 + 64; if (rb >= M) rb = M - 1;
  const float* ga0 = A + (size_t)ra * K + c0;
  const float* ga1 = A + (size_t)rb * K + c0;
  const u16* gb0 = BT + (size_t)(bn + r0) * K + c0;
  const u16* gb1 = BT + (size_t)(bn + r0 + 64) * K + c0;
  u16* lb0 = Bs + wv * 512;
  u16* lb1 = Bs + 2048 + wv * 512;

  const int arow = lane & 15;
  const int kcol = (lane >> 4) * 8;

  // prologue: A-regs for k0 = 0
  float4 fa0 = *(const float4*)(ga0);
  float4 fa1 = *(const float4*)(ga0 + 4);
  float4 fb0 = *(const float4*)(ga1);
  float4 fb1 = *(const float4*)(ga1 + 4);

  for (int k0 = 0; k0 < K; k0 += 32) {
    // A: cvt staged regs -> LDS (elem offset tid*8 == row-major [128][32])
    bf16x8 w0, w1;
    w0[0] = (__bf16)fa0.x; w0[1] = (__bf16)fa0.y; w0[2] = (__bf16)fa0.z; w0[3] = (__bf16)fa0.w;
    w0[4] = (__bf16)fa1.x; w0[5] = (__bf16)fa1.y; w0[6] = (__bf16)fa1.z; w0[7] = (__bf16)fa1.w;
    w1[0] = (__bf16)fb0.x; w1[1] = (__bf16)fb0.y; w1[2] = (__bf16)fb0.z; w1[3] = (__bf16)fb0.w;
    w1[4] = (__bf16)fb1.x; w1[5] = (__bf16)fb1.y; w1[6] = (__bf16)fb1.z; w1[7] = (__bf16)fb1.w;
    *(bf16x8*)(As + tid * 8)        = w0;
    *(bf16x8*)(As + 2048 + tid * 8) = w1;
    // B: async direct-to-LDS
    gllds16(gb0 + k0, lb0);
    gllds16(gb1 + k0, lb1);
    __syncthreads();
    // prefetch next A-regs: latency overlaps the MFMA+ds_read phase
    if (k0 + 32 < K) {
      fa0 = *(const float4*)(ga0 + k0 + 32);
      fa1 = *(const float4*)(ga0 + k0 + 36);
      fb0 = *(const float4*)(ga1 + k0 + 32);
      fb1 = *(const float4*)(ga1 + k0 + 36);
    }
    bf16x8 af[4], bfr[4];
#pragma unroll
    for (int mi = 0; mi < 4; ++mi)
      af[mi] = *(const bf16x8*)(As + (wr + mi * 16 + arow) * 32 + kcol);
#pragma unroll
    for (int ni = 0; ni < 4; ++ni)
      bfr[ni] = *(const bf16x8*)(Bs + (wc + ni * 16 + arow) * 32 + kcol);
#pragma unroll
    for (int mi = 0; mi < 4; ++mi)
#pragma unroll
      for (int ni = 0; ni < 4; ++ni)
        acc[mi][ni] = __builtin_amdgcn_mfma_f32_16x16x32_bf16(af[mi], bfr[ni], acc[mi][ni], 0, 0, 0);
    __syncthreads();
  }

  const int crow = (lane >> 4) * 4;
  const int ccol = lane & 15;
#pragma unroll
  for (int mi = 0; mi < 4; ++mi) {
#pragma unroll
    for (int r = 0; r < 4; ++r) {
      int row = bm + wr + mi * 16 + crow + r;
      if (row < M) {
        u16* cp = Cb + (size_t)row * Nn + bn + wc + ccol;
#pragma unroll
        for (int ni = 0; ni < 4; ++ni) cp[ni * 16] = f2bf(acc[mi][ni][r]);
      }
    }
  }
}

// ---------- bf16 MFMA GEMM: C[M][Nn] = A[M][K] * BT[Nn][K]^T (f32 out) ----------
// bn = blockIdx.x (fast dim) for A-panel HBM reuse.
__global__ __launch_bounds__(256) void k_gemm(const u16* __restrict__ A,
                                              const u16* __restrict__ BT,
                                              float* __restrict__ C,
                                              int M, int Nn, int K) {
  __shared__ u16 As[128 * 32];
  __shared__ u16 Bs[128 * 32];
  const int tid  = threadIdx.x;
  const int lane = tid & 63;
  const int wv   = tid >> 6;
  const int bm = blockIdx.y * 128;   // slow dim
  const int bn = blockIdx.x * 128;   // fast dim
  const int wr = (wv >> 1) * 64;
  const int wc = (wv & 1) * 64;
  const int r0 = tid >> 2;          // 0..63
  const int c0 = (tid & 3) * 8;     // 0,8,16,24 (elements)

  f32x4 acc[4][4];
#pragma unroll
  for (int i = 0; i < 4; ++i)
#pragma unroll
    for (int j = 0; j < 4; ++j) acc[i][j] = (f32x4){0.f, 0.f, 0.f, 0.f};

  int ra = bm + r0;      if (ra >= M) ra = M - 1;
  int rb = bm + r0 + 64; if (rb >= M) rb = M - 1;
  const u16* ga0 = A  + (size_t)ra * K + c0;
  const u16* ga1 = A  + (size_t)rb * K + c0;
  const u16* gb0 = BT + (size_t)(bn + r0) * K + c0;
  const u16* gb1 = BT + (size_t)(bn + r0 + 64) * K + c0;
  u16* la0 = As + wv * 512;
  u16* la1 = As + 2048 + wv * 512;
  u16* lb0 = Bs + wv * 512;
  u16* lb1 = Bs + 2048 + wv * 512;

  const int arow = lane & 15;
  const int kcol = (lane >> 4) * 8;

  for (int k0 = 0; k0 < K; k0 += 32) {
    gllds16(ga0 + k0, la0);
    gllds16(ga1 + k0, la1);
    gllds16(gb0 + k0, lb0);
    gllds16(gb1 + k0, lb1);
    __syncthreads();
    bf16x8 af[4], bfr[4];
#pragma unroll
    for (int mi = 0; mi < 4; ++mi)
      af[mi] = *(const bf16x8*)(As + (wr + mi * 16 + arow) * 32 + kcol);
#pragma unroll
    for (int ni = 0; ni < 4; ++ni)
      bfr[ni] = *(const bf16x8*)(Bs + (wc + ni * 16 + arow) * 32 + kcol);
#pragma unroll
    for (int mi = 0; mi < 4; ++mi)
#pragma unroll
      for (int ni = 0; ni < 4; ++ni)
        acc[mi][ni] = __builtin_amdgcn_mfma_f32_16x16x32_bf16(af[mi], bfr[ni], acc[mi][ni], 0, 0, 0);
    __syncthreads();
  }

  const int crow = (lane >> 4) * 4;
  const int ccol = lane & 15;
#pragma unroll
  for (int mi = 0; mi < 4; ++mi) {
#pragma unroll
    for (int r = 0; r < 4; ++r) {
      int row = bm + wr + mi * 16 + crow + r;
      if (row < M) {
        float* cp = C + (size_t)row * Nn + bn + wc + ccol;
#pragma unroll
        for (int ni = 0; ni < 4; ++ni) cp[ni * 16] = acc[mi][ni][r];
      }
    }
  }
}

// ---------- h2 = h1 @ W2 via split-bf16 MFMA (hi/lo 3-product, ~f32 accuracy) ----------
__global__ __launch_bounds__(256) void k_h2m(const u16* __restrict__ Ahi,
                                             const u16* __restrict__ Alo,
                                             const u16* __restrict__ Bhig,
                                             const u16* __restrict__ Blog,
                                             float* __restrict__ C, int M) {
  __shared__ u16 Bh[32 * 520];   // padded row stride 520: 2-way bank aliasing only
  __shared__ u16 Bl[32 * 520];
  const int tid = threadIdx.x, lane = tid & 63, wv = tid >> 6;
  for (int idx = tid; idx < 2048; idx += 256) {
    int e = idx * 8;
    int row = e >> 9, k = e & 511;
    *(u16x8*)(Bh + row * 520 + k) = *(const u16x8*)(Bhig + e);
    *(u16x8*)(Bl + row * 520 + k) = *(const u16x8*)(Blog + e);
  }
  __syncthreads();

  const int bm = blockIdx.x * 256 + wv * 64;
  const int arow = lane & 15, koff = (lane >> 4) * 8;

  f32x4 acc[4][2];
#pragma unroll
  for (int mi = 0; mi < 4; ++mi)
#pragma unroll
    for (int ni = 0; ni < 2; ++ni) acc[mi][ni] = (f32x4){0.f, 0.f, 0.f, 0.f};

  const u16* pah[4]; const u16* pal[4];
#pragma unroll
  for (int mi = 0; mi < 4; ++mi) {
    int r = bm + mi * 16 + arow; if (r >= M) r = M - 1;
    pah[mi] = Ahi + (size_t)r * DIM_HID + koff;
    pal[mi] = Alo + (size_t)r * DIM_HID + koff;
  }
  const u16* pbh[2]; const u16* pbl[2];
#pragma unroll
  for (int ni = 0; ni < 2; ++ni) {
    pbh[ni] = Bh + (ni * 16 + arow) * 520 + koff;
    pbl[ni] = Bl + (ni * 16 + arow) * 520 + koff;
  }

#pragma unroll
  for (int kk = 0; kk < 16; ++kk) {
    const int k0 = kk * 32;
    bf16x8 ah[4], al[4], bh[2], bl[2];
#pragma unroll
    for (int mi = 0; mi < 4; ++mi) {
      ah[mi] = *(const bf16x8*)(pah[mi] + k0);
      al[mi] = *(const bf16x8*)(pal[mi] + k0);
    }
#pragma unroll
    for (int ni = 0; ni < 2; ++ni) {
      bh[ni] = *(const bf16x8*)(pbh[ni] + k0);
      bl[ni] = *(const bf16x8*)(pbl[ni] + k0);
    }
#pragma unroll
    for (int mi = 0; mi < 4; ++mi)
#pragma unroll
      for (int ni = 0; ni < 2; ++ni) {
        acc[mi][ni] = __builtin_amdgcn_mfma_f32_16x16x32_bf16(ah[mi], bh[ni], acc[mi][ni], 0, 0, 0);
        acc[mi][ni] = __builtin_amdgcn_mfma_f32_16x16x32_bf16(al[mi], bh[ni], acc[mi][ni], 0, 0, 0);
        acc[mi][ni] = __builtin_amdgcn_mfma_f32_16x16x32_bf16(ah[mi], bl[ni], acc[mi][ni], 0, 0, 0);
      }
  }

  const int crow = (lane >> 4) * 4, ccol = lane & 15;
#pragma unroll
  for (int mi = 0; mi < 4; ++mi) {
#pragma unroll
    for (int r = 0; r < 4; ++r) {
      int row = bm + mi * 16 + crow + r;
      if (row < M) {
#pragma unroll
        for (int ni = 0; ni < 2; ++ni) {
          int col = ni * 16 + ccol;
          if (col < DIM_OUT) C[(size_t)row * DIM_OUT + col] = acc[mi][ni][r];
        }
      }
    }
  }
}

// ---------- CSR build ----------
__global__ void k_hist(const int* __restrict__ dst, int* __restrict__ counts, int E) {
  int i = blockIdx.x * blockDim.x + threadIdx.x;
  if (i < E) atomicAdd(&counts[dst[i]], 1);
}

__global__ void k_scan1(const int* __restrict__ counts, int* __restrict__ offs,
                        int* __restrict__ bsums, int n) {
  __shared__ int s[256];
  int i = blockIdx.x * 256 + threadIdx.x;
  int v = (i < n) ? counts[i] : 0;
  s[threadIdx.x] = v;
  __syncthreads();
  for (int d = 1; d < 256; d <<= 1) {
    int t = (threadIdx.x >= d) ? s[threadIdx.x - d] : 0;
    __syncthreads();
    s[threadIdx.x] += t;
    __syncthreads();
  }
  if (i < n) offs[i] = s[threadIdx.x] - v;          // block-local exclusive
  if (threadIdx.x == 255) bsums[blockIdx.x] = s[255];
}

__global__ void k_scan2(int* __restrict__ bsums, int nb) {
  __shared__ int s[256];
  int v = (threadIdx.x < nb) ? bsums[threadIdx.x] : 0;
  s[threadIdx.x] = v;
  __syncthreads();
  for (int d = 1; d < 256; d <<= 1) {
    int t = (threadIdx.x >= d) ? s[threadIdx.x - d] : 0;
    __syncthreads();
    s[threadIdx.x] += t;
    __syncthreads();
  }
  if (threadIdx.x < nb) bsums[threadIdx.x] = s[threadIdx.x] - v;  // exclusive
}

__global__ void k_scan3(int* __restrict__ offs, const int* __restrict__ bsums,
                        int* __restrict__ cursor, int n) {
  int i = blockIdx.x * 256 + threadIdx.x;
  if (i < n) {
    int o = offs[i] + bsums[blockIdx.x];
    offs[i] = o;
    cursor[i] = o;
  }
}

__global__ void k_fill(const int* __restrict__ dst, int* __restrict__ cursor,
                       int* __restrict__ eids, int E) {
  int i = blockIdx.x * blockDim.x + threadIdx.x;
  if (i < E) {
    int p = atomicAdd(&cursor[dst[i]], 1);
    eids[p] = i;
  }
}

// ---------- conv1 FUSED: bf16 h gather, online-softmax aggregation ----------
// Edge indices fetched in PARALLEL across lanes, broadcast via shfl; 2-deep row prefetch.
__global__ __launch_bounds__(256) void k_conv1(
    const u16* __restrict__ hb, const int* __restrict__ src,
    const float* __restrict__ att, const int* __restrict__ offs,
    const int* __restrict__ cnts, const int* __restrict__ eids,
    float* __restrict__ alpha, u16* __restrict__ h1hi, u16* __restrict__ h1lo, int nN) {
  const int lane = threadIdx.x & 63, wv = threadIdx.x >> 6;
  const int nw = gridDim.x * 4;
  for (int v = blockIdx.x * 4 + wv; v < nN; v += nw) {
    const int col = lane * 8;
    u16x8 hd8 = *(const u16x8*)(hb + (size_t)v * DIM_HID + col);
    float hd[8];
#pragma unroll
    for (int i = 0; i < 8; ++i) hd[i] = bf2f(hd8[i]);
    float4 at0 = *(const float4*)(att + col), at1 = *(const float4*)(att + col + 4);
    float at[8] = { at0.x, at0.y, at0.z, at0.w, at1.x, at1.y, at1.z, at1.w };
    const int o = offs[v], deg = cnts[v];
    float m = -1e30f, den = 0.f;
    float c[8] = {0.f,0.f,0.f,0.f,0.f,0.f,0.f,0.f};
    for (int base = 0; base < deg; base += 64) {
      const int nchunk = min(deg - base, 64);
      int myeid = (lane < nchunk) ? eids[o + base + lane] : 0;
      int mysrc = src[myeid];                       // parallel index fetch
      u16x8 r0 = {0,0,0,0,0,0,0,0}, r1 = {0,0,0,0,0,0,0,0};
      int s = __shfl(mysrc, 0, 64);
      r0 = *(const u16x8*)(hb + (size_t)s * DIM_HID + col);
      if (nchunk > 1) {
        s = __shfl(mysrc, 1, 64);
        r1 = *(const u16x8*)(hb + (size_t)s * DIM_HID + col);
      }
      for (int j = 0; j < nchunk; ++j) {
        u16x8 b8 = r0;
        r0 = r1;
        if (j + 2 < nchunk) {                       // 2-deep prefetch
          s = __shfl(mysrc, j + 2, 64);
          r1 = *(const u16x8*)(hb + (size_t)s * DIM_HID + col);
        }
        float bs[8];
#pragma unroll
        for (int i = 0; i < 8; ++i) bs[i] = bf2f(b8[i]);
        float p = 0.f;
#pragma unroll
        for (int i = 0; i < 8; ++i) p += at[i] * lrelu(hd[i] + bs[i]);
#pragma unroll
        for (int msk = 1; msk < 64; msk <<= 1) p += __shfl_xor(p, msk, 64);
        if (lane == 0) alpha[o + base + j] = p;     // raw score, finalized below
        float mn = fmaxf(m, p);
        float sc = __expf(m - mn), w = __expf(p - mn);
        den = den * sc + w;
#pragma unroll
        for (int i = 0; i < 8; ++i) c[i] = c[i] * sc + w * bs[i];
        m = mn;
      }
    }
    const float inv = (deg > 0) ? 1.f / den : 0.f;
    u16x8 hi8, lo8;
#pragma unroll
    for (int i = 0; i < 8; ++i) {
      float rv = elu(c[i] * inv);
      u16 hbv = f2bf(rv);
      hi8[i] = hbv;
      lo8[i] = f2bf(rv - bf2f(hbv));
    }
    *(u16x8*)(h1hi + (size_t)v * DIM_HID + col) = hi8;
    *(u16x8*)(h1lo + (size_t)v * DIM_HID + col) = lo8;
    // finalize alpha: scalar per edge, lane-parallel
    for (int j = lane; j < deg; j += 64)
      alpha[o + j] = __expf(alpha[o + j] - m) * inv;
  }
}

// ---------- conv3 aggregation in 30-dim space ----------
__global__ __launch_bounds__(256) void k_agg30(
    const float* __restrict__ h2, const int* __restrict__ src,
    const int* __restrict__ offs, const int* __restrict__ cnts,
    const int* __restrict__ eids, const float* __restrict__ alpha,
    float* __restrict__ agg30, int nN) {
  int gt = blockIdx.x * 256 + threadIdx.x;
  int v = gt >> 5, d = gt & 31;
  if (v >= nN) return;
  const int o = offs[v], deg = cnts[v];
  float acc = 0.f;
  for (int base = 0; base < deg; base += 32) {
    const int nchunk = min(deg - base, 32);
    int myeid = (d < nchunk) ? eids[o + base + d] : 0;
    int mysrc = src[myeid];
    float myal = (d < nchunk) ? alpha[o + base + d] : 0.f;
    int s = __shfl(mysrc, 0, 32);
    float pv = (d < DIM_OUT) ? h2[(size_t)s * DIM_OUT + d] : 0.f;
    for (int j = 0; j < nchunk; ++j) {
      float hv = pv;
      if (j + 1 < nchunk) {
        s = __shfl(mysrc, j + 1, 32);
        pv = (d < DIM_OUT) ? h2[(size_t)s * DIM_OUT + d] : 0.f;
      }
      acc += __shfl(myal, j, 32) * hv;
    }
  }
  if (d < DIM_OUT) agg30[(size_t)v * DIM_OUT + d] = acc;
}

// ---------- h3 = elu(agg30 @ W2^T) -> bf16  ([N,30]x[30,512]) ----------
__global__ __launch_bounds__(256) void k_g3(const float* __restrict__ agg30,
                                            const float* __restrict__ W2,
                                            u16* __restrict__ h3b, int nN) {
  __shared__ float W2s[DIM_HID * 31];
  for (int i = threadIdx.x; i < DIM_HID * DIM_OUT; i += 256) {
    int k = i / DIM_OUT, c = i - k * DIM_OUT;
    W2s[k * 31 + c] = W2[i];
  }
  __syncthreads();
  const int lane = threadIdx.x & 63, wv = threadIdx.x >> 6;
  const int nw = gridDim.x * 4;
  for (int r = blockIdx.x * 4 + wv; r < nN; r += nw) {
    float hv[DIM_OUT];
    const float* hp = agg30 + (size_t)r * DIM_OUT;
#pragma unroll
    for (int c = 0; c < DIM_OUT; ++c) hv[c] = hp[c];
#pragma unroll
    for (int t = 0; t < 8; ++t) {
      int n = lane + t * 64;
      const float* w = W2s + n * 31;
      float a = 0.f;
#pragma unroll
      for (int c = 0; c < DIM_OUT; ++c) a += hv[c] * w[c];
      h3b[(size_t)r * DIM_HID + n] = f2bf(elu(a));
    }
  }
}

extern "C" void kernel_launch(void* const* d_in, const int* in_sizes, int n_in,
                              void* d_out, int out_size, void* d_ws, size_t ws_size,
                              hipStream_t stream) {
  const float* features = (const float*)d_in[0];
  const int*   eidx     = (const int*)d_in[1];
  const float* W1       = (const float*)d_in[2];
  const float* att1     = (const float*)d_in[3];
  const float* W2       = (const float*)d_in[4];
  const float* W4       = (const float*)d_in[5];
  const int* srcI = eidx;
  const int* dstI = eidx + N_EDGES;
  float* out = (float*)d_out;

  char* ws = (char*)d_ws;
  size_t off = 0;
  auto alloc = [&](size_t b) -> void* {
    void* p = ws + off;
    off += (b + 255) & ~(size_t)255;
    return p;
  };
  u16*   W1T    = (u16*)  alloc((size_t)DIM_HID * DIM_IN * 2);
  u16*   W4T    = (u16*)  alloc((size_t)DIM_IN * DIM_HID * 2);
  u16*   hb     = (u16*)  alloc((size_t)N_NODES * DIM_HID * 2);  // h in bf16
  u16*   h1hi   = (u16*)  alloc((size_t)N_NODES * DIM_HID * 2);
  u16*   h1lo   = (u16*)  alloc((size_t)N_NODES * DIM_HID * 2);
  u16*   h3b    = (u16*)  alloc((size_t)N_NODES * DIM_HID * 2);
  u16*   W2Thi  = (u16*)  alloc((size_t)32 * DIM_HID * 2);
  u16*   W2Tlo  = (u16*)  alloc((size_t)32 * DIM_HID * 2);
  int*   counts = (int*)  alloc((size_t)N_NODES * 4);
  int*   offs   = (int*)  alloc((size_t)N_NODES * 4);
  int*   cursor = (int*)  alloc((size_t)N_NODES * 4);
  int*   bsums  = (int*)  alloc(1024);
  int*   eids   = (int*)  alloc((size_t)N_EDGES * 4);
  float* alpha  = (float*)alloc((size_t)N_EDGES * 4);
  float* agg30  = (float*)alloc((size_t)N_NODES * DIM_OUT * 4);

  // 1. transposed bf16 weights for MFMA B-operand (+ W2T hi/lo)
  k_transpose<<<dim3(DIM_IN / 256, DIM_HID), 256, 0, stream>>>(W1, W1T, DIM_IN, DIM_HID);
  k_transpose<<<dim3(DIM_HID / 256, DIM_IN), 256, 0, stream>>>(W4, W4T, DIM_HID, DIM_IN);
  k_w2t<<<(32 * DIM_HID + 255) / 256, 256, 0, stream>>>(W2, W2Thi, W2Tlo);

  // 2. h = X @ W1 (fused f32->bf16 A staging; bn fast dim for A-panel HBM reuse)
  k_gemm_xw1<<<dim3(DIM_HID / 128, (N_NODES + 127) / 128), 256, 0, stream>>>(
      features, W1T, hb, N_NODES, DIM_HID, DIM_IN);

  // 3. CSR by dst
  hipMemsetAsync(counts, 0, (size_t)N_NODES * 4, stream);
  k_hist<<<(N_EDGES + 255) / 256, 256, 0, stream>>>(dstI, counts, N_EDGES);
  const int nScanBlocks = (N_NODES + 255) / 256;  // 196
  k_scan1<<<nScanBlocks, 256, 0, stream>>>(counts, offs, bsums, N_NODES);
  k_scan2<<<1, 256, 0, stream>>>(bsums, nScanBlocks);
  k_scan3<<<nScanBlocks, 256, 0, stream>>>(offs, bsums, cursor, N_NODES);
  k_fill<<<(N_EDGES + 255) / 256, 256, 0, stream>>>(dstI, cursor, eids, N_EDGES);

  // 4. conv1 fused: scores + online softmax + aggregate + ELU (one bf16 gather pass)
  k_conv1<<<N_NODES / 4, 256, 0, stream>>>(hb, srcI, att1, offs, counts, eids, alpha,
                                           h1hi, h1lo, N_NODES);

  // 5. h2 = h1 @ W2 -> out[0 : N*30) via split-bf16 MFMA
  k_h2m<<<(N_NODES + 255) / 256, 256, 0, stream>>>(h1hi, h1lo, W2Thi, W2Tlo, out, N_NODES);

  // 6. conv3 aggregation in 30-dim space (linearity of aggregate over W2^T)
  k_agg30<<<(N_NODES * 32 + 255) / 256, 256, 0, stream>>>(
      out, srcI, offs, counts, eids, alpha, agg30, N_NODES);

  // 7. h3 = elu(agg30 @ W2^T) -> bf16
  k_g3<<<1024, 256, 0, stream>>>(agg30, W2, h3b, N_NODES);

  // 8. h4 = h3 @ W4 -> out[N*30 : ) (bn fast dim)
  k_gemm<<<dim3(DIM_IN / 128, (N_NODES + 127) / 128), 256, 0, stream>>>(
      h3b, W4T, out + (size_t)N_NODES * DIM_OUT, N_NODES, DIM_IN, DIM_HID);
}